// Round 12
// baseline (362.765 us; speedup 1.0000x reference)
//
#include <hip/hip_runtime.h>
#include <math.h>

#define N_NODES 10000
#define N_EDGES 160000
#define G_SEG 16
#define ZDIM 10
#define KDIM 64
#define NBESS 8
#define HIDR 16
#define RMAXF 5.0f
#define AVG_NEI_F 16.0f
#define TBINS 256

__device__ __forceinline__ float siluf(float x){ float s = 1.0f/(1.0f+expf(-x)); return x*s; }
__device__ __forceinline__ float dsiluf(float x){ float s = 1.0f/(1.0f+expf(-x)); return s*(1.0f + x*(1.0f-s)); }

__device__ __forceinline__ float waveReduce(float v){
  for (int off = 32; off > 0; off >>= 1) v += __shfl_down(v, off);
  return v;
}

__device__ __forceinline__ void r_decode(float r, int& b, float& fr, float& wm){
  wm = (r >= 0.f) ? 1.f : 0.f;
  float tp = fmaxf(r, 0.f) * (TBINS / RMAXF);
  b = (int)tp; if (b > TBINS-1) b = TBINS-1;
  fr = tp - (float)b;
}

// per-node gather, result in a register. Wave-uniform shuffle idx -> readlane.
#define GATHER_NODE(NODE, PTR, PACK, IDXEXPR, LOADH, OUT) { \
  int beg_ = PTR[NODE]; int deg_ = PTR[(NODE)+1] - beg_; \
  float a0_=0.f,a1_=0.f,a2_=0.f,a3_=0.f; \
  for (int base_=0; base_<deg_; base_+=64){ \
    int m_ = min(64, deg_-base_); \
    float r_l = -1.f; int ix_l = 0; \
    if (lane < m_){ int4 pk = PACK[beg_+base_+lane]; r_l = __int_as_float(pk.x); ix_l = IDXEXPR; } \
    int mr_ = (m_ + 7) & ~7; \
    for (int i_=0; i_<mr_; i_+=8){ \
      float r0_=__shfl(r_l,i_),   r1_=__shfl(r_l,i_+1), r2_=__shfl(r_l,i_+2), r3_=__shfl(r_l,i_+3); \
      float r4_=__shfl(r_l,i_+4), r5_=__shfl(r_l,i_+5), r6_=__shfl(r_l,i_+6), r7_=__shfl(r_l,i_+7); \
      int s0_=__shfl(ix_l,i_),   s1_=__shfl(ix_l,i_+1), s2_=__shfl(ix_l,i_+2), s3_=__shfl(ix_l,i_+3); \
      int s4_=__shfl(ix_l,i_+4), s5_=__shfl(ix_l,i_+5), s6_=__shfl(ix_l,i_+6), s7_=__shfl(ix_l,i_+7); \
      int b0_,b1_,b2_,b3_,b4_,b5_,b6_,b7_; \
      float f0_,f1_,f2_,f3_,f4_,f5_,f6_,f7_, w0_,w1_,w2_,w3_,w4_,w5_,w6_,w7_; \
      r_decode(r0_,b0_,f0_,w0_); r_decode(r1_,b1_,f1_,w1_); r_decode(r2_,b2_,f2_,w2_); r_decode(r3_,b3_,f3_,w3_); \
      r_decode(r4_,b4_,f4_,w4_); r_decode(r5_,b5_,f5_,w5_); r_decode(r6_,b6_,f6_,w6_); r_decode(r7_,b7_,f7_,w7_); \
      float2 F0_=Ft2[b0_*KDIM+lane]; float h0_=LOADH(s0_); \
      float2 F1_=Ft2[b1_*KDIM+lane]; float h1_=LOADH(s1_); \
      float2 F2_=Ft2[b2_*KDIM+lane]; float h2_=LOADH(s2_); \
      float2 F3_=Ft2[b3_*KDIM+lane]; float h3_=LOADH(s3_); \
      float2 F4_=Ft2[b4_*KDIM+lane]; float h4_=LOADH(s4_); \
      float2 F5_=Ft2[b5_*KDIM+lane]; float h5_=LOADH(s5_); \
      float2 F6_=Ft2[b6_*KDIM+lane]; float h6_=LOADH(s6_); \
      float2 F7_=Ft2[b7_*KDIM+lane]; float h7_=LOADH(s7_); \
      a0_ += w0_*(F0_.x + f0_*(F0_.y-F0_.x))*h0_; a1_ += w1_*(F1_.x + f1_*(F1_.y-F1_.x))*h1_; \
      a2_ += w2_*(F2_.x + f2_*(F2_.y-F2_.x))*h2_; a3_ += w3_*(F3_.x + f3_*(F3_.y-F3_.x))*h3_; \
      a0_ += w4_*(F4_.x + f4_*(F4_.y-F4_.x))*h4_; a1_ += w5_*(F5_.x + f5_*(F5_.y-F5_.x))*h5_; \
      a2_ += w6_*(F6_.x + f6_*(F6_.y-F6_.x))*h6_; a3_ += w7_*(F7_.x + f7_*(F7_.y-F7_.x))*h7_; \
    } } \
  OUT = ((a0_+a1_)+(a2_+a3_)); }

// K=64 matvec from LDS-staged (or global) weights, 4 independent chains.
#define MV4(V, SW, OUT) { \
  float x0_=0.f,x1_=0.f,x2_=0.f,x3_=0.f; \
  for (int k_=0;k_<KDIM;k_+=4){ \
    x0_ += __shfl(V,k_)  *SW[k_*KDIM+lane]; \
    x1_ += __shfl(V,k_+1)*SW[(k_+1)*KDIM+lane]; \
    x2_ += __shfl(V,k_+2)*SW[(k_+2)*KDIM+lane]; \
    x3_ += __shfl(V,k_+3)*SW[(k_+3)*KDIM+lane]; \
  } OUT = (x0_+x1_)+(x2_+x3_); }

#define STAGE(DST, SRC, N) for (int i_=tid; i_<(N); i_+=1024) DST[i_] = SRC[i_];

#define LOADH_PLAIN(S) rows[(S)*KDIM + lane]
#define LOADH_SM0(S)   sM0[(S)*KDIM + lane]
#define LOADH_G2(S)    gAr2c[(S)*KDIM + lane].x

// ---------------- merged setup ----------------
__global__ __launch_bounds__(256) void k_setup(
    const float* We, const float* Wup, const float* Wsc,
    const float* Wout, const float* Wmix,
    const float* Wr1,
    const float* attrs, const float* aE,
    float* M0, float* Msc0,
    float* WoT0, float* WoT1, float* WmixT0, float* WupT1,
    float* P1, float* Qtab,
    int* z_buf, float* e_node){
  int blk = blockIdx.x, tid = threadIdx.x;
  const float* Wmix1 = Wmix + KDIM*KDIM;
  const float* Wsc1  = Wsc + ZDIM*KDIM*KDIM;
  if (blk < 5){
    int idx = blk*256 + tid;
    if (idx < 1280){
      int which = idx >= 640;
      int t = which ? idx - 640 : idx;
      int z = t >> 6, j = t & 63;
      float acc = 0.f;
      if (!which){
        #pragma unroll 8
        for (int k = 0; k < KDIM; k++) acc += We[z*KDIM + k] * Wup[k*KDIM + j];
        M0[z*KDIM + j] = acc;
      } else {
        #pragma unroll 8
        for (int k = 0; k < KDIM; k++) acc += We[z*KDIM + k] * Wsc[(z*KDIM + k)*KDIM + j];
        Msc0[z*KDIM + j] = acc;
      }
    }
  } else if (blk < 69){
    int t = (blk-5)*256 + tid;   // 0..16383
    int arr = t >> 12;
    int rem = t & 4095;
    int j = rem >> 6, k = rem & 63;
    float v; float* dst;
    switch(arr){
      case 0: v = Wout[k*KDIM + j];                 dst = WoT0;   break;
      case 1: v = Wout[3*KDIM*KDIM + k*KDIM + j];   dst = WoT1;   break;
      case 2: v = Wmix[k*KDIM + j];                 dst = WmixT0; break;
      default:v = Wup[KDIM*KDIM + k*KDIM + j];      dst = WupT1;  break;
    }
    dst[rem] = v;
  } else if (blk < 73){
    int t = (blk-69)*256 + tid;  // 0..1023
    int h = t >> 6, k = t & 63;
    float acc = 0.f;
    #pragma unroll 8
    for (int j = 0; j < KDIM; j++) acc += Wr1[j*HIDR + h] * Wmix1[k*KDIM + j];
    P1[h*KDIM + k] = acc;
  } else if (blk < 113){
    int t = (blk-73)*256 + tid;  // 0..10239
    int z = t >> 10;
    int rem = t & 1023;
    int h = rem >> 6, k = rem & 63;
    float acc = 0.f;
    #pragma unroll 8
    for (int j = 0; j < KDIM; j++) acc += Wr1[j*HIDR + h] * Wsc1[(z*KDIM + k)*KDIM + j];
    Qtab[(z*HIDR + h)*KDIM + k] = acc;
  } else {
    int n = (blk-113)*256 + tid;
    if (n < N_NODES){
      int z = 0;
      for (int i = 1; i < ZDIM; i++) if (attrs[n*ZDIM+i] > 0.5f) z = i;
      z_buf[n] = z;
      e_node[n] = aE[z];
    }
  }
}

__global__ __launch_bounds__(256) void k_edge_setup(const float* pos, const float* shifts, const int* ei,
                                                    const int* z_buf,
                                                    float4* evec, int4* emeta,
                                                    int* cnt_r, int* cnt_s){
  int e = blockIdx.x*256 + threadIdx.x;
  int s = ei[e], rcv = ei[N_EDGES + e];
  float dx = pos[rcv*3+0] - pos[s*3+0] + shifts[e*3+0];
  float dy = pos[rcv*3+1] - pos[s*3+1] + shifts[e*3+1];
  float dz = pos[rcv*3+2] - pos[s*3+2] + shifts[e*3+2];
  float r = sqrtf(dx*dx + dy*dy + dz*dz + 1e-9f);
  evec[e] = make_float4(dx, dy, dz, r);
  emeta[e] = make_int4(__float_as_int(r), s, rcv, z_buf[s]);
  if (r < RMAXF){
    atomicAdd(&cnt_s[s], 1);
    atomicAdd(&cnt_r[rcv], 1);
  }
}

__global__ __launch_bounds__(1024) void k_scan(const int* cnt_r, int* ptr_r, int* cur_r,
                                               const int* cnt_s, int* ptr_s, int* cur_s){
  __shared__ int part[1024];
  int tid = threadIdx.x;
  const int* cnt = blockIdx.x ? cnt_s : cnt_r;
  int* ptr = blockIdx.x ? ptr_s : ptr_r;
  int* cur = blockIdx.x ? cur_s : cur_r;
  const int per = 10;
  int start = tid*per;
  int s = 0;
  for (int t = 0; t < per; t++){ int i = start + t; if (i < N_NODES) s += cnt[i]; }
  part[tid] = s; __syncthreads();
  for (int d = 1; d < 1024; d <<= 1){
    int v = (tid >= d) ? part[tid-d] : 0;
    __syncthreads();
    part[tid] += v;
    __syncthreads();
  }
  int run = part[tid] - s;
  for (int t = 0; t < per; t++){
    int i = start + t;
    if (i < N_NODES){ ptr[i] = run; cur[i] = run; run += cnt[i]; }
  }
  if (tid == 1023) ptr[N_NODES] = part[1023];
}

__global__ __launch_bounds__(256) void k_fill(const int4* emeta, int* cur_r, int* cur_s,
                                              int4* pr_pack, int4* ps_pack){
  int e = blockIdx.x*256 + threadIdx.x;
  int4 m = emeta[e];            // {r_bits, snd, rcv, ez}
  float r = __int_as_float(m.x);
  if (r >= RMAXF) return;
  int p = atomicAdd(&cur_s[m.y], 1);
  ps_pack[p] = make_int4(m.x, m.z, e, 0);          // {r, rcv, eid}
  int p2 = atomicAdd(&cur_r[m.z], 1);
  pr_pack[p2] = make_int4(m.x, m.y, m.w, e);       // {r, snd, ez, eid}
}

// ---------------- radial-MLP tables ----------------
__global__ __launch_bounds__(64) void k_table(const float* R1g, const float* R2g,
                                              const float* R3g, const float* R4g,
                                              float2* Ft2_0, float2* Ft2_1, float* dF4f){
  int t = blockIdx.x, j = threadIdx.x;
  __shared__ float efs[NBESS], defs[NBESS];
  __shared__ float xs[KDIM], dxs[KDIM];
  if (j < NBESS){
    double r = (double)t * (double)RMAXF / (double)TBINS;
    double w = (double)(j+1) * M_PI / (double)RMAXF;
    double c = sqrt(2.0 / (double)RMAXF);
    double bess, dbess;
    if (r < 1e-12){ bess = c*w; dbess = 0.0; }
    else {
      double sw = sin(w*r), cw = cos(w*r);
      bess = c*sw/r;
      dbess = c*(w*cw*r - sw)/(r*r);
    }
    double xx = r / (double)RMAXF;
    double f = 0.0, df = 0.0;
    if (xx < 1.0){
      double x2 = xx*xx, x4 = x2*x2, x5 = x4*xx, x6 = x5*xx, x7 = x6*xx;
      f = 1.0 - 21.0*x5 + 35.0*x6 - 15.0*x7;
      df = (-105.0*x4 + 210.0*x5 - 105.0*x6) / (double)RMAXF;
    }
    efs[j]  = (float)(bess*f);
    defs[j] = (float)(dbess*f + bess*df);
  }
  __syncthreads();
  for (int i = 0; i < 2; i++){
    const float* R1 = R1g + i*NBESS*KDIM;
    const float* R2 = R2g + i*KDIM*KDIM;
    const float* R3 = R3g + i*KDIM*KDIM;
    const float* R4 = R4g + i*KDIM*KDIM;
    float z = 0.f, dz = 0.f;
    for (int b = 0; b < NBESS; b++){ float w = R1[b*KDIM+j]; z += efs[b]*w; dz += defs[b]*w; }
    float v = siluf(z), dv = dsiluf(z)*dz;
    xs[j] = v; dxs[j] = dv; __syncthreads();
    z = 0.f; dz = 0.f;
    for (int k = 0; k < KDIM; k++){ float w = R2[k*KDIM+j]; z += xs[k]*w; dz += dxs[k]*w; }
    v = siluf(z); dv = dsiluf(z)*dz; __syncthreads();
    xs[j] = v; dxs[j] = dv; __syncthreads();
    z = 0.f; dz = 0.f;
    for (int k = 0; k < KDIM; k++){ float w = R3[k*KDIM+j]; z += xs[k]*w; dz += dxs[k]*w; }
    v = siluf(z); dv = dsiluf(z)*dz; __syncthreads();
    xs[j] = v; dxs[j] = dv; __syncthreads();
    z = 0.f; dz = 0.f;
    for (int k = 0; k < KDIM; k++){ float w = R4[k*KDIM+j]; z += xs[k]*w; dz += dxs[k]*w; }
    float2* Ft  = i ? Ft2_1 : Ft2_0;
    Ft[t*KDIM+j].x = z;  if (t > 0) Ft[(t-1)*KDIM+j].y = z;
    dF4f[(t*KDIM+j)*4 + 2*i] = dz;
    if (t > 0) dF4f[((t-1)*KDIM+j)*4 + 2*i + 1] = dz;
    __syncthreads();
  }
}

// ---------------- layer-0: 16 waves/block, LDS-staged weights, 1 node/wave ----------------
__global__ __launch_bounds__(1024) void k_layer0_fwd(
    const int* z_buf, const int* ptr_r, const int4* pr_pack,
    const float2* Ft2, const float* M0,
    const float* Wout0, const float* theta0, const float* Wmix0,
    const float* Msc0, const float* w_read0,
    const float* Wup1, const float* Wsc1,
    float* A0_out, float* h1, float* sc1, float* e_node){
  __shared__ float sWout[KDIM*KDIM], sWmix[KDIM*KDIM], sWup[KDIM*KDIM];
  __shared__ float sM0[ZDIM*KDIM], sMsc0[ZDIM*KDIM];
  int tid = threadIdx.x;
  STAGE(sWout, Wout0, KDIM*KDIM)
  STAGE(sWmix, Wmix0, KDIM*KDIM)
  STAGE(sWup,  Wup1,  KDIM*KDIM)
  STAGE(sM0,   M0,    ZDIM*KDIM)
  STAGE(sMsc0, Msc0,  ZDIM*KDIM)
  __syncthreads();
  int w = tid >> 6, lane = tid & 63;
  int node = blockIdx.x*16 + w;
  int z = z_buf[node];
  float acc;
  GATHER_NODE(node, ptr_r, pr_pack, pk.z, LOADH_SM0, acc)
  acc *= (1.0f/AVG_NEI_F);
  float a0;
  MV4(acc, sWout, a0)
  A0_out[node*KDIM+lane] = a0;
  float t0 = theta0[(0*ZDIM+z)*KDIM+lane];
  float t1 = theta0[(1*ZDIM+z)*KDIM+lane];
  float t2 = theta0[(2*ZDIM+z)*KDIM+lane];
  float v = (t0 + t1*a0 + t2*a0*a0)*a0;
  float f;
  MV4(v, sWmix, f)
  f += sMsc0[z*KDIM+lane];
  float p = waveReduce(f * w_read0[lane]);
  if (lane == 0) e_node[node] += p;
  float h;
  MV4(f, sWup, h)
  h1[node*KDIM+lane] = h;
  const float* Wz = Wsc1 + z*KDIM*KDIM;
  float s;
  MV4(f, Wz, s)
  sc1[node*KDIM+lane] = s;
}

// ---------------- layer-1 fwd + node-local bwd: 16 waves/block, LDS weights ----------------
__global__ __launch_bounds__(1024) void k_layer1_fwd_bwd(
    const int* z_buf, const int* ptr_r, const int4* pr_pack,
    const float2* Ft2, const float* h1,
    const float* Wout1, const float* theta1, const float* Wmix1,
    const float* sc1, const float* Wr1, const float* Wr2,
    const float* P1, const float* Qtab, const float* WoT1, const float* w_read0,
    float2* gAr2, float* gF1, float* e_node){
  __shared__ float sWout[KDIM*KDIM], sWmix[KDIM*KDIM], sWoT[KDIM*KDIM];
  __shared__ float sP1[HIDR*KDIM], sWr1[KDIM*HIDR];
  int tid = threadIdx.x;
  STAGE(sWout, Wout1, KDIM*KDIM)
  STAGE(sWmix, Wmix1, KDIM*KDIM)
  STAGE(sWoT,  WoT1,  KDIM*KDIM)
  STAGE(sP1,   P1,    HIDR*KDIM)
  STAGE(sWr1,  Wr1,   KDIM*HIDR)
  __syncthreads();
  int w = tid >> 6, lane = tid & 63;
  int node = blockIdx.x*16 + w;
  int z = z_buf[node];
  const float* rows = h1;
  float acc;
  GATHER_NODE(node, ptr_r, pr_pack, pk.y, LOADH_PLAIN, acc)
  acc *= (1.0f/AVG_NEI_F);
  float a0;
  MV4(acc, sWout, a0)
  float t0 = theta1[(0*ZDIM+z)*KDIM+lane];
  float t1 = theta1[(1*ZDIM+z)*KDIM+lane];
  float t2 = theta1[(2*ZDIM+z)*KDIM+lane];
  float v = (t0 + t1*a0 + t2*a0*a0)*a0;
  float f;
  MV4(v, sWmix, f)
  f += sc1[node*KDIM+lane];
  // readout: t[hh] = sum_j f[j]*Wr1[j][hh]
  int hh = lane & 15;
  float tp0 = 0.f, tp1 = 0.f;
  for (int j = 0; j < KDIM; j += 2){
    tp0 += __shfl(f,j)  *sWr1[j*HIDR+hh];
    tp1 += __shfl(f,j+1)*sWr1[(j+1)*HIDR+hh];
  }
  float tpart = tp0 + tp1;
  float wr2 = Wr2[hh];
  float ne = waveReduce(siluf(tpart)*wr2);
  if (lane == 0) e_node[node] += 0.25f*ne;
  // backward through readout (low-rank shortcut)
  float coeff = dsiluf(tpart)*wr2;
  float gP0=0.f, gP1=0.f, gs0=0.f, gs1=0.f;
  const float* Qz = Qtab + z*HIDR*KDIM;
  #pragma unroll
  for (int h2 = 0; h2 < HIDR; h2 += 2){
    float c0 = __shfl(coeff, h2), c1 = __shfl(coeff, h2+1);
    gP0 += c0*sP1[h2*KDIM+lane];
    gP1 += c1*sP1[(h2+1)*KDIM+lane];
    gs0 += c0*Qz[h2*KDIM+lane];
    gs1 += c1*Qz[(h2+1)*KDIM+lane];
  }
  gF1[node*KDIM+lane] = w_read0[lane] + gs0 + gs1;
  float u = t0 + 2.f*t1*a0 + 3.f*t2*a0*a0;
  float vl = (gP0+gP1)*u;
  float gAr;
  MV4(vl, sWoT, gAr)
  gAr2[node*KDIM+lane].x = gAr * (1.0f/AVG_NEI_F);
}

// LDS pre-reduced energy
__global__ __launch_bounds__(256) void k_energy(const float* e_node, const int* batch, float* out_e){
  __shared__ float part[G_SEG];
  int tid = threadIdx.x;
  if (tid < G_SEG) part[tid] = 0.f;
  __syncthreads();
  int n = blockIdx.x*256 + tid;
  if (n < N_NODES) atomicAdd(&part[batch[n]], e_node[n]);
  __syncthreads();
  if (tid < G_SEG) atomicAdd(&out_e[tid], part[tid]);
}

// ---------------- bwd: sender-gather gH + layer-0 node bwd: 16 waves/block, LDS weights ----------------
__global__ __launch_bounds__(1024) void k_bwd_gH0(
    const int* z_buf, const int* ptr_s, const int4* ps_pack,
    const float2* Ft2, const float2* gAr2c, const float* WupT1, const float* gF1,
    const float* A00, const float* WmixT0, const float* WoT0, const float* theta0,
    float2* gAr2){
  __shared__ float sWupT[KDIM*KDIM], sWmixT[KDIM*KDIM], sWoT[KDIM*KDIM];
  int tid = threadIdx.x;
  STAGE(sWupT, WupT1, KDIM*KDIM)
  STAGE(sWmixT, WmixT0, KDIM*KDIM)
  STAGE(sWoT, WoT0, KDIM*KDIM)
  __syncthreads();
  int w = tid >> 6, lane = tid & 63;
  int node = blockIdx.x*16 + w;
  float ga;
  GATHER_NODE(node, ptr_s, ps_pack, pk.y, LOADH_G2, ga)
  float gfh;
  MV4(ga, sWupT, gfh)
  float gt = gF1[node*KDIM+lane] + gfh;
  float gP;
  MV4(gt, sWmixT, gP)
  int z = z_buf[node];
  float a = A00[node*KDIM+lane];
  float t0 = theta0[(0*ZDIM+z)*KDIM+lane];
  float t1 = theta0[(1*ZDIM+z)*KDIM+lane];
  float t2 = theta0[(2*ZDIM+z)*KDIM+lane];
  float u = t0 + 2.f*t1*a + 3.f*t2*a*a;
  float vl = gP*u;
  float gAr;
  MV4(vl, sWoT, gAr)
  gAr2[node*KDIM+lane].y = gAr * (1.0f/AVG_NEI_F);
}

// per-edge gr/r -> evec[e].w  (one wave per edge; NO atomics)
__global__ __launch_bounds__(256) void k_gr(const int4* emeta, const float4* dF4,
                                            const float2* gAr2, const float* h1, const float* M0,
                                            float4* evec){
  int tid = threadIdx.x;
  int w = tid>>6, lane = tid&63;
  int e = blockIdx.x*4 + w;
  int4 m = emeta[e];              // {r, snd, rcv, ez}
  float r = __int_as_float(m.x);
  if (r >= RMAXF) return;
  float tp = r * (TBINS / RMAXF);
  int b = (int)tp; if (b > TBINS-1) b = TBINS-1;
  float fr = tp - (float)b;
  float4 d4 = dF4[b*KDIM + lane];
  float2 g  = gAr2[m.z*KDIM + lane];
  float hv1 = h1[m.y*KDIM + lane];
  float hv0 = M0[m.w*KDIM + lane];
  float v = g.x*hv1*(d4.z + fr*(d4.w - d4.z)) + g.y*hv0*(d4.x + fr*(d4.y - d4.x));
  v = waveReduce(v);
  if (lane == 0) evec[e].w = v / r;
}

// force gather: 16 lanes/node, both CSR lists, no atomics
__global__ __launch_bounds__(256) void k_force(const int* ptr_r, const int4* pr_pack,
                                               const int* ptr_s, const int4* ps_pack,
                                               const float4* evec,
                                               float* out_f){
  int tid = threadIdx.x;
  int node = blockIdx.x*16 + (tid >> 4);
  int li = tid & 15;
  float fx=0.f, fy=0.f, fz=0.f;
  int beg = ptr_r[node], end = ptr_r[node+1];
  for (int idx = beg + li; idx < end; idx += 16){
    int e = pr_pack[idx].w;
    float4 ev = evec[e];
    fx -= ev.w*ev.x; fy -= ev.w*ev.y; fz -= ev.w*ev.z;
  }
  beg = ptr_s[node]; end = ptr_s[node+1];
  for (int idx = beg + li; idx < end; idx += 16){
    int e = ps_pack[idx].z;
    float4 ev = evec[e];
    fx += ev.w*ev.x; fy += ev.w*ev.y; fz += ev.w*ev.z;
  }
  #pragma unroll
  for (int off = 8; off > 0; off >>= 1){
    fx += __shfl_xor(fx, off);
    fy += __shfl_xor(fy, off);
    fz += __shfl_xor(fz, off);
  }
  if (li == 0){
    out_f[node*3+0] = fx; out_f[node*3+1] = fy; out_f[node*3+2] = fz;
  }
}

extern "C" void kernel_launch(void* const* d_in, const int* in_sizes, int n_in,
                              void* d_out, int out_size, void* d_ws, size_t ws_size,
                              hipStream_t stream){
  const float* pos    = (const float*)d_in[0];
  const float* attrs  = (const float*)d_in[1];
  const float* shifts = (const float*)d_in[2];
  const float* aE     = (const float*)d_in[3];
  const float* We     = (const float*)d_in[4];
  const float* Wup    = (const float*)d_in[5];
  const float* R1     = (const float*)d_in[6];
  const float* R2     = (const float*)d_in[7];
  const float* R3     = (const float*)d_in[8];
  const float* R4     = (const float*)d_in[9];
  const float* Wout   = (const float*)d_in[10];
  const float* Wsc    = (const float*)d_in[11];
  const float* theta  = (const float*)d_in[12];
  const float* Wmix   = (const float*)d_in[13];
  const float* w_read0= (const float*)d_in[14];
  const float* Wr1    = (const float*)d_in[15];
  const float* Wr2    = (const float*)d_in[16];
  const int*   ei     = (const int*)d_in[17];
  const int*   batch  = (const int*)d_in[18];

  char* base = (char*)d_ws;
  size_t off = 0;
  auto alloc = [&](size_t bytes)->void*{
    void* p = base + off;
    off = (off + bytes + 255) & ~(size_t)255;
    return p;
  };
  float4* evec   = (float4*)alloc(N_EDGES*sizeof(float4));
  int4*   emeta  = (int4*)alloc(N_EDGES*sizeof(int4));
  int4*   pr_pack= (int4*)alloc(N_EDGES*sizeof(int4));
  int4*   ps_pack= (int4*)alloc(N_EDGES*sizeof(int4));
  float*  e_node = (float*)alloc(N_NODES*sizeof(float));
  float*  h1     = (float*)alloc(N_NODES*KDIM*sizeof(float));
  float*  sc1    = (float*)alloc(N_NODES*KDIM*sizeof(float));
  float*  A00    = (float*)alloc(N_NODES*KDIM*sizeof(float));
  float*  gF1    = (float*)alloc(N_NODES*KDIM*sizeof(float));
  float2* gAr2   = (float2*)alloc(N_NODES*KDIM*sizeof(float2));
  float2* Ft2_0  = (float2*)alloc((TBINS+1)*KDIM*sizeof(float2));
  float2* Ft2_1  = (float2*)alloc((TBINS+1)*KDIM*sizeof(float2));
  float4* dF4    = (float4*)alloc((TBINS+1)*KDIM*sizeof(float4));
  float*  M0     = (float*)alloc(ZDIM*KDIM*sizeof(float));
  float*  Msc0   = (float*)alloc(ZDIM*KDIM*sizeof(float));
  float*  WoT0   = (float*)alloc(KDIM*KDIM*sizeof(float));
  float*  WoT1   = (float*)alloc(KDIM*KDIM*sizeof(float));
  float*  WmixT0 = (float*)alloc(KDIM*KDIM*sizeof(float));
  float*  WupT1  = (float*)alloc(KDIM*KDIM*sizeof(float));
  float*  P1     = (float*)alloc(HIDR*KDIM*sizeof(float));
  float*  Qtab   = (float*)alloc(ZDIM*HIDR*KDIM*sizeof(float));
  int* z_buf = (int*)alloc(N_NODES*sizeof(int));
  int* cnt_r = (int*)alloc(N_NODES*sizeof(int));
  int* cnt_s = (int*)alloc(N_NODES*sizeof(int));
  int* ptr_r = (int*)alloc((N_NODES+1)*sizeof(int));
  int* ptr_s = (int*)alloc((N_NODES+1)*sizeof(int));
  int* cur_r = (int*)alloc(N_NODES*sizeof(int));
  int* cur_s = (int*)alloc(N_NODES*sizeof(int));

  float* out_e = (float*)d_out;
  float* out_f = out_e + G_SEG;

  hipMemsetAsync(d_out, 0, (size_t)out_size*sizeof(float), stream);
  hipMemsetAsync(cnt_r, 0, N_NODES*sizeof(int), stream);
  hipMemsetAsync(cnt_s, 0, N_NODES*sizeof(int), stream);

  const int NB16 = N_NODES/16;  // 625 blocks x 16 waves (1 node/wave)
  const int EB  = N_EDGES/256;
  const int EB4 = N_EDGES/4;
  const int NBt = (N_NODES+255)/256;

  const float* Wup1 = Wup + KDIM*KDIM;
  const float* Wsc1 = Wsc + ZDIM*KDIM*KDIM;
  const float* Wout1 = Wout + 3*KDIM*KDIM;
  const float* theta1 = theta + 3*ZDIM*KDIM;
  const float* Wmix1 = Wmix + KDIM*KDIM;

  k_setup<<<153,256,0,stream>>>(We, Wup, Wsc, Wout, Wmix, Wr1, attrs, aE,
                                M0, Msc0, WoT0, WoT1, WmixT0, WupT1, P1, Qtab,
                                z_buf, e_node);
  k_table<<<TBINS+1,64,0,stream>>>(R1, R2, R3, R4, Ft2_0, Ft2_1, (float*)dF4);
  k_edge_setup<<<EB,256,0,stream>>>(pos, shifts, ei, z_buf, evec, emeta, cnt_r, cnt_s);
  k_scan<<<2,1024,0,stream>>>(cnt_r, ptr_r, cur_r, cnt_s, ptr_s, cur_s);
  k_fill<<<EB,256,0,stream>>>(emeta, cur_r, cur_s, pr_pack, ps_pack);

  // ---- forward ----
  k_layer0_fwd<<<NB16,1024,0,stream>>>(z_buf, ptr_r, pr_pack, Ft2_0, M0,
      Wout, theta, Wmix, Msc0, w_read0, Wup1, Wsc1,
      A00, h1, sc1, e_node);
  k_layer1_fwd_bwd<<<NB16,1024,0,stream>>>(z_buf, ptr_r, pr_pack, Ft2_1, h1,
      Wout1, theta1, Wmix1, sc1, Wr1, Wr2,
      P1, Qtab, WoT1, w_read0,
      gAr2, gF1, e_node);
  k_energy<<<NBt,256,0,stream>>>(e_node, batch, out_e);

  // ---- backward ----
  k_bwd_gH0<<<NB16,1024,0,stream>>>(z_buf, ptr_s, ps_pack, Ft2_1, gAr2, WupT1, gF1,
      A00, WmixT0, WoT0, theta, gAr2);
  k_gr<<<EB4,256,0,stream>>>(emeta, dF4, gAr2, h1, M0, evec);
  k_force<<<N_NODES/16,256,0,stream>>>(ptr_r, pr_pack, ptr_s, ps_pack, evec, out_f);
}

// Round 13
// 268.893 us; speedup vs baseline: 1.3491x; 1.3491x over previous
//
#include <hip/hip_runtime.h>
#include <math.h>

#define N_NODES 10000
#define N_EDGES 160000
#define G_SEG 16
#define ZDIM 10
#define KDIM 64
#define NBESS 8
#define HIDR 16
#define RMAXF 5.0f
#define AVG_NEI_F 16.0f
#define TBINS 256

__device__ __forceinline__ float siluf(float x){ float s = 1.0f/(1.0f+expf(-x)); return x*s; }
__device__ __forceinline__ float dsiluf(float x){ float s = 1.0f/(1.0f+expf(-x)); return s*(1.0f + x*(1.0f-s)); }

__device__ __forceinline__ float waveReduce(float v){
  for (int off = 32; off > 0; off >>= 1) v += __shfl_down(v, off);
  return v;
}

__device__ __forceinline__ void r_decode(float r, int& b, float& fr, float& wm){
  wm = (r >= 0.f) ? 1.f : 0.f;
  float tp = fmaxf(r, 0.f) * (TBINS / RMAXF);
  b = (int)tp; if (b > TBINS-1) b = TBINS-1;
  fr = tp - (float)b;
}

// per-node gather, result in a register. Wave-uniform shuffle idx -> readlane.
#define GATHER_NODE(NODE, PTR, PACK, IDXEXPR, LOADH, OUT) { \
  int beg_ = PTR[NODE]; int deg_ = PTR[(NODE)+1] - beg_; \
  float a0_=0.f,a1_=0.f,a2_=0.f,a3_=0.f; \
  for (int base_=0; base_<deg_; base_+=64){ \
    int m_ = min(64, deg_-base_); \
    float r_l = -1.f; int ix_l = 0; \
    if (lane < m_){ int4 pk = PACK[beg_+base_+lane]; r_l = __int_as_float(pk.x); ix_l = IDXEXPR; } \
    int mr_ = (m_ + 7) & ~7; \
    for (int i_=0; i_<mr_; i_+=8){ \
      float r0_=__shfl(r_l,i_),   r1_=__shfl(r_l,i_+1), r2_=__shfl(r_l,i_+2), r3_=__shfl(r_l,i_+3); \
      float r4_=__shfl(r_l,i_+4), r5_=__shfl(r_l,i_+5), r6_=__shfl(r_l,i_+6), r7_=__shfl(r_l,i_+7); \
      int s0_=__shfl(ix_l,i_),   s1_=__shfl(ix_l,i_+1), s2_=__shfl(ix_l,i_+2), s3_=__shfl(ix_l,i_+3); \
      int s4_=__shfl(ix_l,i_+4), s5_=__shfl(ix_l,i_+5), s6_=__shfl(ix_l,i_+6), s7_=__shfl(ix_l,i_+7); \
      int b0_,b1_,b2_,b3_,b4_,b5_,b6_,b7_; \
      float f0_,f1_,f2_,f3_,f4_,f5_,f6_,f7_, w0_,w1_,w2_,w3_,w4_,w5_,w6_,w7_; \
      r_decode(r0_,b0_,f0_,w0_); r_decode(r1_,b1_,f1_,w1_); r_decode(r2_,b2_,f2_,w2_); r_decode(r3_,b3_,f3_,w3_); \
      r_decode(r4_,b4_,f4_,w4_); r_decode(r5_,b5_,f5_,w5_); r_decode(r6_,b6_,f6_,w6_); r_decode(r7_,b7_,f7_,w7_); \
      float2 F0_=Ft2[b0_*KDIM+lane]; float h0_=LOADH(s0_); \
      float2 F1_=Ft2[b1_*KDIM+lane]; float h1_=LOADH(s1_); \
      float2 F2_=Ft2[b2_*KDIM+lane]; float h2_=LOADH(s2_); \
      float2 F3_=Ft2[b3_*KDIM+lane]; float h3_=LOADH(s3_); \
      float2 F4_=Ft2[b4_*KDIM+lane]; float h4_=LOADH(s4_); \
      float2 F5_=Ft2[b5_*KDIM+lane]; float h5_=LOADH(s5_); \
      float2 F6_=Ft2[b6_*KDIM+lane]; float h6_=LOADH(s6_); \
      float2 F7_=Ft2[b7_*KDIM+lane]; float h7_=LOADH(s7_); \
      a0_ += w0_*(F0_.x + f0_*(F0_.y-F0_.x))*h0_; a1_ += w1_*(F1_.x + f1_*(F1_.y-F1_.x))*h1_; \
      a2_ += w2_*(F2_.x + f2_*(F2_.y-F2_.x))*h2_; a3_ += w3_*(F3_.x + f3_*(F3_.y-F3_.x))*h3_; \
      a0_ += w4_*(F4_.x + f4_*(F4_.y-F4_.x))*h4_; a1_ += w5_*(F5_.x + f5_*(F5_.y-F5_.x))*h5_; \
      a2_ += w6_*(F6_.x + f6_*(F6_.y-F6_.x))*h6_; a3_ += w7_*(F7_.x + f7_*(F7_.y-F7_.x))*h7_; \
    } } \
  OUT = ((a0_+a1_)+(a2_+a3_)); }

// cooperative block matvec: 4 waves, 4 nodes; wave w loads W rows [16w,16w+16)
// ONCE and accumulates partials for all 4 nodes; combine via 1KB LDS.
// W-row L1 traffic per block: 16KB (was 64KB with per-wave matvecs).
#define COOPMV(INV, W, OUTV) { \
  lds_in[w][lane] = INV; \
  __syncthreads(); \
  { float p0_=0.f,p1_=0.f,p2_=0.f,p3__=0.f; \
    const float* Wb_ = (W) + (w*16)*KDIM + lane; \
    _Pragma("unroll") \
    for (int kk_=0; kk_<16; kk_++){ \
      float wrow_ = Wb_[kk_*KDIM]; \
      int k_ = w*16 + kk_; \
      p0_  += lds_in[0][k_]*wrow_; \
      p1_  += lds_in[1][k_]*wrow_; \
      p2_  += lds_in[2][k_]*wrow_; \
      p3__ += lds_in[3][k_]*wrow_; \
    } \
    lds_part[w][0][lane]=p0_; lds_part[w][1][lane]=p1_; \
    lds_part[w][2][lane]=p2_; lds_part[w][3][lane]=p3__; } \
  __syncthreads(); \
  OUTV = ((lds_part[0][w][lane]+lds_part[1][w][lane]) + \
          (lds_part[2][w][lane]+lds_part[3][w][lane])); }

// per-wave K=64 matvec from register V via uniform shfl (for z-dependent W)
#define MV4R(V, W, OUT) { \
  float x0_=0.f,x1_=0.f,x2_=0.f,x3_=0.f; \
  for (int k_=0;k_<KDIM;k_+=4){ \
    x0_ += __shfl(V,k_)  *W[k_*KDIM+lane]; \
    x1_ += __shfl(V,k_+1)*W[(k_+1)*KDIM+lane]; \
    x2_ += __shfl(V,k_+2)*W[(k_+2)*KDIM+lane]; \
    x3_ += __shfl(V,k_+3)*W[(k_+3)*KDIM+lane]; \
  } OUT = (x0_+x1_)+(x2_+x3_); }

#define LOADH_PLAIN(S) rows[(S)*KDIM + lane]
#define LOADH_G2(S)    gAr2c[(S)*KDIM + lane].x

// ---------------- merged setup ----------------
__global__ __launch_bounds__(256) void k_setup(
    const float* We, const float* Wup, const float* Wsc,
    const float* Wout, const float* Wmix,
    const float* Wr1,
    const float* attrs, const float* aE,
    float* M0, float* Msc0,
    float* WoT0, float* WoT1, float* WmixT0, float* WupT1,
    float* P1, float* Qtab,
    int* z_buf, float* e_node){
  int blk = blockIdx.x, tid = threadIdx.x;
  const float* Wmix1 = Wmix + KDIM*KDIM;
  const float* Wsc1  = Wsc + ZDIM*KDIM*KDIM;
  if (blk < 5){
    int idx = blk*256 + tid;
    if (idx < 1280){
      int which = idx >= 640;
      int t = which ? idx - 640 : idx;
      int z = t >> 6, j = t & 63;
      float acc = 0.f;
      if (!which){
        #pragma unroll 8
        for (int k = 0; k < KDIM; k++) acc += We[z*KDIM + k] * Wup[k*KDIM + j];
        M0[z*KDIM + j] = acc;
      } else {
        #pragma unroll 8
        for (int k = 0; k < KDIM; k++) acc += We[z*KDIM + k] * Wsc[(z*KDIM + k)*KDIM + j];
        Msc0[z*KDIM + j] = acc;
      }
    }
  } else if (blk < 69){
    int t = (blk-5)*256 + tid;   // 0..16383
    int arr = t >> 12;
    int rem = t & 4095;
    int j = rem >> 6, k = rem & 63;
    float v; float* dst;
    switch(arr){
      case 0: v = Wout[k*KDIM + j];                 dst = WoT0;   break;
      case 1: v = Wout[3*KDIM*KDIM + k*KDIM + j];   dst = WoT1;   break;
      case 2: v = Wmix[k*KDIM + j];                 dst = WmixT0; break;
      default:v = Wup[KDIM*KDIM + k*KDIM + j];      dst = WupT1;  break;
    }
    dst[rem] = v;
  } else if (blk < 73){
    int t = (blk-69)*256 + tid;  // 0..1023
    int h = t >> 6, k = t & 63;
    float acc = 0.f;
    #pragma unroll 8
    for (int j = 0; j < KDIM; j++) acc += Wr1[j*HIDR + h] * Wmix1[k*KDIM + j];
    P1[h*KDIM + k] = acc;
  } else if (blk < 113){
    int t = (blk-73)*256 + tid;  // 0..10239
    int z = t >> 10;
    int rem = t & 1023;
    int h = rem >> 6, k = rem & 63;
    float acc = 0.f;
    #pragma unroll 8
    for (int j = 0; j < KDIM; j++) acc += Wr1[j*HIDR + h] * Wsc1[(z*KDIM + k)*KDIM + j];
    Qtab[(z*HIDR + h)*KDIM + k] = acc;
  } else {
    int n = (blk-113)*256 + tid;
    if (n < N_NODES){
      int z = 0;
      for (int i = 1; i < ZDIM; i++) if (attrs[n*ZDIM+i] > 0.5f) z = i;
      z_buf[n] = z;
      e_node[n] = aE[z];
    }
  }
}

__global__ __launch_bounds__(256) void k_edge_setup(const float* pos, const float* shifts, const int* ei,
                                                    const int* z_buf,
                                                    float4* evec, int4* emeta,
                                                    int* cnt_r, int* cnt_s){
  int e = blockIdx.x*256 + threadIdx.x;
  int s = ei[e], rcv = ei[N_EDGES + e];
  float dx = pos[rcv*3+0] - pos[s*3+0] + shifts[e*3+0];
  float dy = pos[rcv*3+1] - pos[s*3+1] + shifts[e*3+1];
  float dz = pos[rcv*3+2] - pos[s*3+2] + shifts[e*3+2];
  float r = sqrtf(dx*dx + dy*dy + dz*dz + 1e-9f);
  evec[e] = make_float4(dx, dy, dz, r);
  emeta[e] = make_int4(__float_as_int(r), s, rcv, z_buf[s]);
  if (r < RMAXF){
    atomicAdd(&cnt_s[s], 1);
    atomicAdd(&cnt_r[rcv], 1);
  }
}

__global__ __launch_bounds__(1024) void k_scan(const int* cnt_r, int* ptr_r, int* cur_r,
                                               const int* cnt_s, int* ptr_s, int* cur_s){
  __shared__ int part[1024];
  int tid = threadIdx.x;
  const int* cnt = blockIdx.x ? cnt_s : cnt_r;
  int* ptr = blockIdx.x ? ptr_s : ptr_r;
  int* cur = blockIdx.x ? cur_s : cur_r;
  const int per = 10;
  int start = tid*per;
  int s = 0;
  for (int t = 0; t < per; t++){ int i = start + t; if (i < N_NODES) s += cnt[i]; }
  part[tid] = s; __syncthreads();
  for (int d = 1; d < 1024; d <<= 1){
    int v = (tid >= d) ? part[tid-d] : 0;
    __syncthreads();
    part[tid] += v;
    __syncthreads();
  }
  int run = part[tid] - s;
  for (int t = 0; t < per; t++){
    int i = start + t;
    if (i < N_NODES){ ptr[i] = run; cur[i] = run; run += cnt[i]; }
  }
  if (tid == 1023) ptr[N_NODES] = part[1023];
}

__global__ __launch_bounds__(256) void k_fill(const int4* emeta, int* cur_r, int* cur_s,
                                              int4* pr_pack, int4* ps_pack){
  int e = blockIdx.x*256 + threadIdx.x;
  int4 m = emeta[e];            // {r_bits, snd, rcv, ez}
  float r = __int_as_float(m.x);
  if (r >= RMAXF) return;
  int p = atomicAdd(&cur_s[m.y], 1);
  ps_pack[p] = make_int4(m.x, m.z, e, 0);          // {r, rcv, eid}
  int p2 = atomicAdd(&cur_r[m.z], 1);
  pr_pack[p2] = make_int4(m.x, m.y, m.w, e);       // {r, snd, ez, eid}
}

// ---------------- radial-MLP tables (parallel over layer x bin) ----------------
__global__ __launch_bounds__(64) void k_table(const float* R1g, const float* R2g,
                                              const float* R3g, const float* R4g,
                                              float2* Ft2_0, float2* Ft2_1, float* dF4f){
  int blk = blockIdx.x;
  int i = blk / (TBINS+1);           // layer
  int t = blk % (TBINS+1);           // bin
  int j = threadIdx.x;
  __shared__ float efs[NBESS], defs[NBESS];
  __shared__ float xs[KDIM], dxs[KDIM];
  if (j < NBESS){
    double r = (double)t * (double)RMAXF / (double)TBINS;
    double w = (double)(j+1) * M_PI / (double)RMAXF;
    double c = sqrt(2.0 / (double)RMAXF);
    double bess, dbess;
    if (r < 1e-12){ bess = c*w; dbess = 0.0; }
    else {
      double sw = sin(w*r), cw = cos(w*r);
      bess = c*sw/r;
      dbess = c*(w*cw*r - sw)/(r*r);
    }
    double xx = r / (double)RMAXF;
    double f = 0.0, df = 0.0;
    if (xx < 1.0){
      double x2 = xx*xx, x4 = x2*x2, x5 = x4*xx, x6 = x5*xx, x7 = x6*xx;
      f = 1.0 - 21.0*x5 + 35.0*x6 - 15.0*x7;
      df = (-105.0*x4 + 210.0*x5 - 105.0*x6) / (double)RMAXF;
    }
    efs[j]  = (float)(bess*f);
    defs[j] = (float)(dbess*f + bess*df);
  }
  __syncthreads();
  const float* R1 = R1g + i*NBESS*KDIM;
  const float* R2 = R2g + i*KDIM*KDIM;
  const float* R3 = R3g + i*KDIM*KDIM;
  const float* R4 = R4g + i*KDIM*KDIM;
  float z = 0.f, dz = 0.f;
  for (int b = 0; b < NBESS; b++){ float w = R1[b*KDIM+j]; z += efs[b]*w; dz += defs[b]*w; }
  float v = siluf(z), dv = dsiluf(z)*dz;
  xs[j] = v; dxs[j] = dv; __syncthreads();
  z = 0.f; dz = 0.f;
  for (int k = 0; k < KDIM; k++){ float w = R2[k*KDIM+j]; z += xs[k]*w; dz += dxs[k]*w; }
  v = siluf(z); dv = dsiluf(z)*dz; __syncthreads();
  xs[j] = v; dxs[j] = dv; __syncthreads();
  z = 0.f; dz = 0.f;
  for (int k = 0; k < KDIM; k++){ float w = R3[k*KDIM+j]; z += xs[k]*w; dz += dxs[k]*w; }
  v = siluf(z); dv = dsiluf(z)*dz; __syncthreads();
  xs[j] = v; dxs[j] = dv; __syncthreads();
  z = 0.f; dz = 0.f;
  for (int k = 0; k < KDIM; k++){ float w = R4[k*KDIM+j]; z += xs[k]*w; dz += dxs[k]*w; }
  float2* Ft  = i ? Ft2_1 : Ft2_0;
  Ft[t*KDIM+j].x = z;  if (t > 0) Ft[(t-1)*KDIM+j].y = z;
  dF4f[(t*KDIM+j)*4 + 2*i] = dz;
  if (t > 0) dF4f[((t-1)*KDIM+j)*4 + 2*i + 1] = dz;
}

// ---------------- layer-0: gather + cooperative epilogue ----------------
__global__ __launch_bounds__(256) void k_layer0_fwd(
    const int* z_buf, const int* ptr_r, const int4* pr_pack,
    const float2* Ft2, const float* M0,
    const float* Wout0, const float* theta0, const float* Wmix0,
    const float* Msc0, const float* w_read0,
    const float* Wup1, const float* Wsc1,
    float* A0_out, float* h1, float* sc1, float* e_node){
  __shared__ float lds_in[4][KDIM];
  __shared__ float lds_part[4][4][KDIM];
  int tid = threadIdx.x;
  int w = tid >> 6, lane = tid & 63;
  int node = blockIdx.x*4 + w;
  int z = z_buf[node];
  const float* rows = M0;
  float acc;
  GATHER_NODE(node, ptr_r, pr_pack, pk.z, LOADH_PLAIN, acc)
  acc *= (1.0f/AVG_NEI_F);
  float a0;
  COOPMV(acc, Wout0, a0)
  A0_out[node*KDIM+lane] = a0;
  float t0 = theta0[(0*ZDIM+z)*KDIM+lane];
  float t1 = theta0[(1*ZDIM+z)*KDIM+lane];
  float t2 = theta0[(2*ZDIM+z)*KDIM+lane];
  float v = (t0 + t1*a0 + t2*a0*a0)*a0;
  float f;
  COOPMV(v, Wmix0, f)
  f += Msc0[z*KDIM+lane];
  float p = waveReduce(f * w_read0[lane]);
  if (lane == 0) e_node[node] += p;
  float h;
  COOPMV(f, Wup1, h)
  h1[node*KDIM+lane] = h;
  const float* Wz = Wsc1 + z*KDIM*KDIM;   // z-dependent: per-wave
  float s;
  MV4R(f, Wz, s)
  sc1[node*KDIM+lane] = s;
}

// ---------------- layer-1 fwd + node-local bwd ----------------
__global__ __launch_bounds__(256) void k_layer1_fwd_bwd(
    const int* z_buf, const int* ptr_r, const int4* pr_pack,
    const float2* Ft2, const float* h1,
    const float* Wout1, const float* theta1, const float* Wmix1,
    const float* sc1, const float* Wr1, const float* Wr2,
    const float* P1, const float* Qtab, const float* WoT1, const float* w_read0,
    float2* gAr2, float* gF1, float* e_node){
  __shared__ float lds_in[4][KDIM];
  __shared__ float lds_part[4][4][KDIM];
  int tid = threadIdx.x;
  int w = tid >> 6, lane = tid & 63;
  int node = blockIdx.x*4 + w;
  int z = z_buf[node];
  const float* rows = h1;
  float acc;
  GATHER_NODE(node, ptr_r, pr_pack, pk.y, LOADH_PLAIN, acc)
  acc *= (1.0f/AVG_NEI_F);
  float a0;
  COOPMV(acc, Wout1, a0)
  float t0 = theta1[(0*ZDIM+z)*KDIM+lane];
  float t1 = theta1[(1*ZDIM+z)*KDIM+lane];
  float t2 = theta1[(2*ZDIM+z)*KDIM+lane];
  float v = (t0 + t1*a0 + t2*a0*a0)*a0;
  float f;
  COOPMV(v, Wmix1, f)
  f += sc1[node*KDIM+lane];
  // readout: t[hh] = sum_j f[j]*Wr1[j][hh]  (hh=lane&15, replicated x4)
  int hh = lane & 15;
  float tp0 = 0.f, tp1 = 0.f;
  for (int j = 0; j < KDIM; j += 2){
    tp0 += __shfl(f,j)  *Wr1[j*HIDR+hh];
    tp1 += __shfl(f,j+1)*Wr1[(j+1)*HIDR+hh];
  }
  float tpart = tp0 + tp1;
  float wr2 = Wr2[hh];
  float ne = waveReduce(siluf(tpart)*wr2);
  if (lane == 0) e_node[node] += 0.25f*ne;
  // backward through readout (low-rank shortcut)
  float coeff = dsiluf(tpart)*wr2;
  float gP0=0.f, gP1=0.f, gs0=0.f, gs1=0.f;
  const float* Qz = Qtab + z*HIDR*KDIM;
  #pragma unroll
  for (int h2 = 0; h2 < HIDR; h2 += 2){
    float c0 = __shfl(coeff, h2), c1 = __shfl(coeff, h2+1);
    gP0 += c0*P1[h2*KDIM+lane];
    gP1 += c1*P1[(h2+1)*KDIM+lane];
    gs0 += c0*Qz[h2*KDIM+lane];
    gs1 += c1*Qz[(h2+1)*KDIM+lane];
  }
  gF1[node*KDIM+lane] = w_read0[lane] + gs0 + gs1;
  float u = t0 + 2.f*t1*a0 + 3.f*t2*a0*a0;
  float vl = (gP0+gP1)*u;
  float gAr;
  COOPMV(vl, WoT1, gAr)
  gAr2[node*KDIM+lane].x = gAr * (1.0f/AVG_NEI_F);
}

// LDS pre-reduced energy
__global__ __launch_bounds__(256) void k_energy(const float* e_node, const int* batch, float* out_e){
  __shared__ float part[G_SEG];
  int tid = threadIdx.x;
  if (tid < G_SEG) part[tid] = 0.f;
  __syncthreads();
  int n = blockIdx.x*256 + tid;
  if (n < N_NODES) atomicAdd(&part[batch[n]], e_node[n]);
  __syncthreads();
  if (tid < G_SEG) atomicAdd(&out_e[tid], part[tid]);
}

// ---------------- bwd: sender-gather gH + layer-0 node bwd ----------------
__global__ __launch_bounds__(256) void k_bwd_gH0(
    const int* z_buf, const int* ptr_s, const int4* ps_pack,
    const float2* Ft2, const float2* gAr2c, const float* WupT1, const float* gF1,
    const float* A00, const float* WmixT0, const float* WoT0, const float* theta0,
    float2* gAr2){
  __shared__ float lds_in[4][KDIM];
  __shared__ float lds_part[4][4][KDIM];
  int tid = threadIdx.x;
  int w = tid >> 6, lane = tid & 63;
  int node = blockIdx.x*4 + w;
  float ga;
  GATHER_NODE(node, ptr_s, ps_pack, pk.y, LOADH_G2, ga)
  float gfh;
  COOPMV(ga, WupT1, gfh)
  float gt = gF1[node*KDIM+lane] + gfh;
  float gP;
  COOPMV(gt, WmixT0, gP)
  int z = z_buf[node];
  float a = A00[node*KDIM+lane];
  float t0 = theta0[(0*ZDIM+z)*KDIM+lane];
  float t1 = theta0[(1*ZDIM+z)*KDIM+lane];
  float t2 = theta0[(2*ZDIM+z)*KDIM+lane];
  float u = t0 + 2.f*t1*a + 3.f*t2*a*a;
  float vl = gP*u;
  float gAr;
  COOPMV(vl, WoT0, gAr)
  gAr2[node*KDIM+lane].y = gAr * (1.0f/AVG_NEI_F);
}

// per-edge gr/r -> evec[e].w  (one wave per edge; NO atomics)
__global__ __launch_bounds__(256) void k_gr(const int4* emeta, const float4* dF4,
                                            const float2* gAr2, const float* h1, const float* M0,
                                            float4* evec){
  int tid = threadIdx.x;
  int w = tid>>6, lane = tid&63;
  int e = blockIdx.x*4 + w;
  int4 m = emeta[e];              // {r, snd, rcv, ez}
  float r = __int_as_float(m.x);
  if (r >= RMAXF) return;
  float tp = r * (TBINS / RMAXF);
  int b = (int)tp; if (b > TBINS-1) b = TBINS-1;
  float fr = tp - (float)b;
  float4 d4 = dF4[b*KDIM + lane];
  float2 g  = gAr2[m.z*KDIM + lane];
  float hv1 = h1[m.y*KDIM + lane];
  float hv0 = M0[m.w*KDIM + lane];
  float v = g.x*hv1*(d4.z + fr*(d4.w - d4.z)) + g.y*hv0*(d4.x + fr*(d4.y - d4.x));
  v = waveReduce(v);
  if (lane == 0) evec[e].w = v / r;
}

// force gather: 16 lanes/node, both CSR lists, no atomics
__global__ __launch_bounds__(256) void k_force(const int* ptr_r, const int4* pr_pack,
                                               const int* ptr_s, const int4* ps_pack,
                                               const float4* evec,
                                               float* out_f){
  int tid = threadIdx.x;
  int node = blockIdx.x*16 + (tid >> 4);
  int li = tid & 15;
  float fx=0.f, fy=0.f, fz=0.f;
  int beg = ptr_r[node], end = ptr_r[node+1];
  for (int idx = beg + li; idx < end; idx += 16){
    int e = pr_pack[idx].w;
    float4 ev = evec[e];
    fx -= ev.w*ev.x; fy -= ev.w*ev.y; fz -= ev.w*ev.z;
  }
  beg = ptr_s[node]; end = ptr_s[node+1];
  for (int idx = beg + li; idx < end; idx += 16){
    int e = ps_pack[idx].z;
    float4 ev = evec[e];
    fx += ev.w*ev.x; fy += ev.w*ev.y; fz += ev.w*ev.z;
  }
  #pragma unroll
  for (int off = 8; off > 0; off >>= 1){
    fx += __shfl_xor(fx, off);
    fy += __shfl_xor(fy, off);
    fz += __shfl_xor(fz, off);
  }
  if (li == 0){
    out_f[node*3+0] = fx; out_f[node*3+1] = fy; out_f[node*3+2] = fz;
  }
}

extern "C" void kernel_launch(void* const* d_in, const int* in_sizes, int n_in,
                              void* d_out, int out_size, void* d_ws, size_t ws_size,
                              hipStream_t stream){
  const float* pos    = (const float*)d_in[0];
  const float* attrs  = (const float*)d_in[1];
  const float* shifts = (const float*)d_in[2];
  const float* aE     = (const float*)d_in[3];
  const float* We     = (const float*)d_in[4];
  const float* Wup    = (const float*)d_in[5];
  const float* R1     = (const float*)d_in[6];
  const float* R2     = (const float*)d_in[7];
  const float* R3     = (const float*)d_in[8];
  const float* R4     = (const float*)d_in[9];
  const float* Wout   = (const float*)d_in[10];
  const float* Wsc    = (const float*)d_in[11];
  const float* theta  = (const float*)d_in[12];
  const float* Wmix   = (const float*)d_in[13];
  const float* w_read0= (const float*)d_in[14];
  const float* Wr1    = (const float*)d_in[15];
  const float* Wr2    = (const float*)d_in[16];
  const int*   ei     = (const int*)d_in[17];
  const int*   batch  = (const int*)d_in[18];

  char* base = (char*)d_ws;
  size_t off = 0;
  auto alloc = [&](size_t bytes)->void*{
    void* p = base + off;
    off = (off + bytes + 255) & ~(size_t)255;
    return p;
  };
  float4* evec   = (float4*)alloc(N_EDGES*sizeof(float4));
  int4*   emeta  = (int4*)alloc(N_EDGES*sizeof(int4));
  int4*   pr_pack= (int4*)alloc(N_EDGES*sizeof(int4));
  int4*   ps_pack= (int4*)alloc(N_EDGES*sizeof(int4));
  float*  e_node = (float*)alloc(N_NODES*sizeof(float));
  float*  h1     = (float*)alloc(N_NODES*KDIM*sizeof(float));
  float*  sc1    = (float*)alloc(N_NODES*KDIM*sizeof(float));
  float*  A00    = (float*)alloc(N_NODES*KDIM*sizeof(float));
  float*  gF1    = (float*)alloc(N_NODES*KDIM*sizeof(float));
  float2* gAr2   = (float2*)alloc(N_NODES*KDIM*sizeof(float2));
  float2* Ft2_0  = (float2*)alloc((TBINS+1)*KDIM*sizeof(float2));
  float2* Ft2_1  = (float2*)alloc((TBINS+1)*KDIM*sizeof(float2));
  float4* dF4    = (float4*)alloc((TBINS+1)*KDIM*sizeof(float4));
  float*  M0     = (float*)alloc(ZDIM*KDIM*sizeof(float));
  float*  Msc0   = (float*)alloc(ZDIM*KDIM*sizeof(float));
  float*  WoT0   = (float*)alloc(KDIM*KDIM*sizeof(float));
  float*  WoT1   = (float*)alloc(KDIM*KDIM*sizeof(float));
  float*  WmixT0 = (float*)alloc(KDIM*KDIM*sizeof(float));
  float*  WupT1  = (float*)alloc(KDIM*KDIM*sizeof(float));
  float*  P1     = (float*)alloc(HIDR*KDIM*sizeof(float));
  float*  Qtab   = (float*)alloc(ZDIM*HIDR*KDIM*sizeof(float));
  int* z_buf = (int*)alloc(N_NODES*sizeof(int));
  int* cnt_r = (int*)alloc(N_NODES*sizeof(int));
  int* cnt_s = (int*)alloc(N_NODES*sizeof(int));
  int* ptr_r = (int*)alloc((N_NODES+1)*sizeof(int));
  int* ptr_s = (int*)alloc((N_NODES+1)*sizeof(int));
  int* cur_r = (int*)alloc(N_NODES*sizeof(int));
  int* cur_s = (int*)alloc(N_NODES*sizeof(int));

  float* out_e = (float*)d_out;
  float* out_f = out_e + G_SEG;

  hipMemsetAsync(d_out, 0, (size_t)out_size*sizeof(float), stream);
  hipMemsetAsync(cnt_r, 0, N_NODES*sizeof(int), stream);
  hipMemsetAsync(cnt_s, 0, N_NODES*sizeof(int), stream);

  const int NB4 = N_NODES/4;
  const int EB  = N_EDGES/256;
  const int EB4 = N_EDGES/4;
  const int NBt = (N_NODES+255)/256;

  const float* Wup1 = Wup + KDIM*KDIM;
  const float* Wsc1 = Wsc + ZDIM*KDIM*KDIM;
  const float* Wout1 = Wout + 3*KDIM*KDIM;
  const float* theta1 = theta + 3*ZDIM*KDIM;
  const float* Wmix1 = Wmix + KDIM*KDIM;

  k_setup<<<153,256,0,stream>>>(We, Wup, Wsc, Wout, Wmix, Wr1, attrs, aE,
                                M0, Msc0, WoT0, WoT1, WmixT0, WupT1, P1, Qtab,
                                z_buf, e_node);
  k_table<<<2*(TBINS+1),64,0,stream>>>(R1, R2, R3, R4, Ft2_0, Ft2_1, (float*)dF4);
  k_edge_setup<<<EB,256,0,stream>>>(pos, shifts, ei, z_buf, evec, emeta, cnt_r, cnt_s);
  k_scan<<<2,1024,0,stream>>>(cnt_r, ptr_r, cur_r, cnt_s, ptr_s, cur_s);
  k_fill<<<EB,256,0,stream>>>(emeta, cur_r, cur_s, pr_pack, ps_pack);

  // ---- forward ----
  k_layer0_fwd<<<NB4,256,0,stream>>>(z_buf, ptr_r, pr_pack, Ft2_0, M0,
      Wout, theta, Wmix, Msc0, w_read0, Wup1, Wsc1,
      A00, h1, sc1, e_node);
  k_layer1_fwd_bwd<<<NB4,256,0,stream>>>(z_buf, ptr_r, pr_pack, Ft2_1, h1,
      Wout1, theta1, Wmix1, sc1, Wr1, Wr2,
      P1, Qtab, WoT1, w_read0,
      gAr2, gF1, e_node);
  k_energy<<<NBt,256,0,stream>>>(e_node, batch, out_e);

  // ---- backward ----
  k_bwd_gH0<<<NB4,256,0,stream>>>(z_buf, ptr_s, ps_pack, Ft2_1, gAr2, WupT1, gF1,
      A00, WmixT0, WoT0, theta, gAr2);
  k_gr<<<EB4,256,0,stream>>>(emeta, dF4, gAr2, h1, M0, evec);
  k_force<<<N_NODES/16,256,0,stream>>>(ptr_r, pr_pack, ptr_s, ps_pack, evec, out_f);
}

// Round 14
// 265.432 us; speedup vs baseline: 1.3667x; 1.0130x over previous
//
#include <hip/hip_runtime.h>
#include <math.h>

#define N_NODES 10000
#define N_EDGES 160000
#define G_SEG 16
#define ZDIM 10
#define KDIM 64
#define NBESS 8
#define HIDR 16
#define RMAXF 5.0f
#define AVG_NEI_F 16.0f
#define TBINS 256

__device__ __forceinline__ float siluf(float x){ float s = 1.0f/(1.0f+expf(-x)); return x*s; }
__device__ __forceinline__ float dsiluf(float x){ float s = 1.0f/(1.0f+expf(-x)); return s*(1.0f + x*(1.0f-s)); }

__device__ __forceinline__ float waveReduce(float v){
  for (int off = 32; off > 0; off >>= 1) v += __shfl_down(v, off);
  return v;
}

__device__ __forceinline__ void r_decode(float r, int& b, float& fr, float& wm){
  wm = (r >= 0.f) ? 1.f : 0.f;
  float tp = fmaxf(r, 0.f) * (TBINS / RMAXF);
  b = (int)tp; if (b > TBINS-1) b = TBINS-1;
  fr = tp - (float)b;
}

// per-node gather, result in a register. Wave-uniform shuffle idx -> readlane.
#define GATHER_NODE(NODE, PTR, PACK, IDXEXPR, LOADH, OUT) { \
  int beg_ = PTR[NODE]; int deg_ = PTR[(NODE)+1] - beg_; \
  float a0_=0.f,a1_=0.f,a2_=0.f,a3_=0.f; \
  for (int base_=0; base_<deg_; base_+=64){ \
    int m_ = min(64, deg_-base_); \
    float r_l = -1.f; int ix_l = 0; \
    if (lane < m_){ int4 pk = PACK[beg_+base_+lane]; r_l = __int_as_float(pk.x); ix_l = IDXEXPR; } \
    int mr_ = (m_ + 7) & ~7; \
    for (int i_=0; i_<mr_; i_+=8){ \
      float r0_=__shfl(r_l,i_),   r1_=__shfl(r_l,i_+1), r2_=__shfl(r_l,i_+2), r3_=__shfl(r_l,i_+3); \
      float r4_=__shfl(r_l,i_+4), r5_=__shfl(r_l,i_+5), r6_=__shfl(r_l,i_+6), r7_=__shfl(r_l,i_+7); \
      int s0_=__shfl(ix_l,i_),   s1_=__shfl(ix_l,i_+1), s2_=__shfl(ix_l,i_+2), s3_=__shfl(ix_l,i_+3); \
      int s4_=__shfl(ix_l,i_+4), s5_=__shfl(ix_l,i_+5), s6_=__shfl(ix_l,i_+6), s7_=__shfl(ix_l,i_+7); \
      int b0_,b1_,b2_,b3_,b4_,b5_,b6_,b7_; \
      float f0_,f1_,f2_,f3_,f4_,f5_,f6_,f7_, w0_,w1_,w2_,w3_,w4_,w5_,w6_,w7_; \
      r_decode(r0_,b0_,f0_,w0_); r_decode(r1_,b1_,f1_,w1_); r_decode(r2_,b2_,f2_,w2_); r_decode(r3_,b3_,f3_,w3_); \
      r_decode(r4_,b4_,f4_,w4_); r_decode(r5_,b5_,f5_,w5_); r_decode(r6_,b6_,f6_,w6_); r_decode(r7_,b7_,f7_,w7_); \
      float2 F0_=Ft2[b0_*KDIM+lane]; float h0_=LOADH(s0_); \
      float2 F1_=Ft2[b1_*KDIM+lane]; float h1_=LOADH(s1_); \
      float2 F2_=Ft2[b2_*KDIM+lane]; float h2_=LOADH(s2_); \
      float2 F3_=Ft2[b3_*KDIM+lane]; float h3_=LOADH(s3_); \
      float2 F4_=Ft2[b4_*KDIM+lane]; float h4_=LOADH(s4_); \
      float2 F5_=Ft2[b5_*KDIM+lane]; float h5_=LOADH(s5_); \
      float2 F6_=Ft2[b6_*KDIM+lane]; float h6_=LOADH(s6_); \
      float2 F7_=Ft2[b7_*KDIM+lane]; float h7_=LOADH(s7_); \
      a0_ += w0_*(F0_.x + f0_*(F0_.y-F0_.x))*h0_; a1_ += w1_*(F1_.x + f1_*(F1_.y-F1_.x))*h1_; \
      a2_ += w2_*(F2_.x + f2_*(F2_.y-F2_.x))*h2_; a3_ += w3_*(F3_.x + f3_*(F3_.y-F3_.x))*h3_; \
      a0_ += w4_*(F4_.x + f4_*(F4_.y-F4_.x))*h4_; a1_ += w5_*(F5_.x + f5_*(F5_.y-F5_.x))*h5_; \
      a2_ += w6_*(F6_.x + f6_*(F6_.y-F6_.x))*h6_; a3_ += w7_*(F7_.x + f7_*(F7_.y-F7_.x))*h7_; \
    } } \
  OUT = ((a0_+a1_)+(a2_+a3_)); }

// cooperative block matvec: 4 waves, 4 nodes; wave w loads W rows [16w,16w+16)
// ONCE and accumulates partials for all 4 nodes; combine via LDS.
#define COOPMV(INV, W, OUTV) { \
  lds_in[w][lane] = INV; \
  __syncthreads(); \
  { float p0_=0.f,p1_=0.f,p2_=0.f,p3__=0.f; \
    const float* Wb_ = (W) + (w*16)*KDIM + lane; \
    _Pragma("unroll") \
    for (int kk_=0; kk_<16; kk_++){ \
      float wrow_ = Wb_[kk_*KDIM]; \
      int k_ = w*16 + kk_; \
      p0_  += lds_in[0][k_]*wrow_; \
      p1_  += lds_in[1][k_]*wrow_; \
      p2_  += lds_in[2][k_]*wrow_; \
      p3__ += lds_in[3][k_]*wrow_; \
    } \
    lds_part[w][0][lane]=p0_; lds_part[w][1][lane]=p1_; \
    lds_part[w][2][lane]=p2_; lds_part[w][3][lane]=p3__; } \
  __syncthreads(); \
  OUTV = ((lds_part[0][w][lane]+lds_part[1][w][lane]) + \
          (lds_part[2][w][lane]+lds_part[3][w][lane])); }

// per-wave K=64 matvec from register V via uniform shfl (for z-dependent W)
#define MV4R(V, W, OUT) { \
  float x0_=0.f,x1_=0.f,x2_=0.f,x3_=0.f; \
  for (int k_=0;k_<KDIM;k_+=4){ \
    x0_ += __shfl(V,k_)  *W[k_*KDIM+lane]; \
    x1_ += __shfl(V,k_+1)*W[(k_+1)*KDIM+lane]; \
    x2_ += __shfl(V,k_+2)*W[(k_+2)*KDIM+lane]; \
    x3_ += __shfl(V,k_+3)*W[(k_+3)*KDIM+lane]; \
  } OUT = (x0_+x1_)+(x2_+x3_); }

#define LOADH_PLAIN(S) rows[(S)*KDIM + lane]
#define LOADH_G2(S)    gAr2c[(S)*KDIM + lane].x

#define NTABW 514            // 2 layers x 257 bins, one wave each
#define SETUP_BASE 153
#define NSETUP (SETUP_BASE + (NTABW+3)/4)   // 153 + 129 = 282 blocks

// ---------------- merged setup + wave-local table build ----------------
__global__ __launch_bounds__(256) void k_setup(
    const float* We, const float* Wup, const float* Wsc,
    const float* Wout, const float* Wmix,
    const float* Wr1,
    const float* attrs, const float* aE,
    const float* R1g, const float* R2g, const float* R3g, const float* R4g,
    float* M0, float* Msc0,
    float* WoT0, float* WoT1, float* WmixT0, float* WupT1,
    float* P1, float* Qtab,
    float2* Ft2_0, float2* Ft2_1, float* dF4f,
    int* z_buf, float* e_node){
  int blk = blockIdx.x, tid = threadIdx.x;
  const float* Wmix1 = Wmix + KDIM*KDIM;
  const float* Wsc1  = Wsc + ZDIM*KDIM*KDIM;
  if (blk < 5){
    int idx = blk*256 + tid;
    if (idx < 1280){
      int which = idx >= 640;
      int t = which ? idx - 640 : idx;
      int z = t >> 6, j = t & 63;
      float acc = 0.f;
      if (!which){
        #pragma unroll 8
        for (int k = 0; k < KDIM; k++) acc += We[z*KDIM + k] * Wup[k*KDIM + j];
        M0[z*KDIM + j] = acc;
      } else {
        #pragma unroll 8
        for (int k = 0; k < KDIM; k++) acc += We[z*KDIM + k] * Wsc[(z*KDIM + k)*KDIM + j];
        Msc0[z*KDIM + j] = acc;
      }
    }
  } else if (blk < 69){
    int t = (blk-5)*256 + tid;   // 0..16383
    int arr = t >> 12;
    int rem = t & 4095;
    int j = rem >> 6, k = rem & 63;
    float v; float* dst;
    switch(arr){
      case 0: v = Wout[k*KDIM + j];                 dst = WoT0;   break;
      case 1: v = Wout[3*KDIM*KDIM + k*KDIM + j];   dst = WoT1;   break;
      case 2: v = Wmix[k*KDIM + j];                 dst = WmixT0; break;
      default:v = Wup[KDIM*KDIM + k*KDIM + j];      dst = WupT1;  break;
    }
    dst[rem] = v;
  } else if (blk < 73){
    int t = (blk-69)*256 + tid;  // 0..1023
    int h = t >> 6, k = t & 63;
    float acc = 0.f;
    #pragma unroll 8
    for (int j = 0; j < KDIM; j++) acc += Wr1[j*HIDR + h] * Wmix1[k*KDIM + j];
    P1[h*KDIM + k] = acc;
  } else if (blk < 113){
    int t = (blk-73)*256 + tid;  // 0..10239
    int z = t >> 10;
    int rem = t & 1023;
    int h = rem >> 6, k = rem & 63;
    float acc = 0.f;
    #pragma unroll 8
    for (int j = 0; j < KDIM; j++) acc += Wr1[j*HIDR + h] * Wsc1[(z*KDIM + k)*KDIM + j];
    Qtab[(z*HIDR + h)*KDIM + k] = acc;
  } else if (blk < SETUP_BASE){
    int n = (blk-113)*256 + tid;
    if (n < N_NODES){
      int z = 0;
      for (int i = 1; i < ZDIM; i++) if (attrs[n*ZDIM+i] > 0.5f) z = i;
      z_buf[n] = z;
      e_node[n] = aE[z];
    }
  } else {
    // wave-local radial-MLP table build: one (layer,bin) per wave, no barriers
    int w = tid >> 6, j = tid & 63;
    int wave_id = (blk - SETUP_BASE)*4 + w;
    if (wave_id >= NTABW) return;
    int i = wave_id / (TBINS+1);
    int t = wave_id % (TBINS+1);
    // Bessel basis value (lane j<8 meaningful, others garbage but unused)
    float efv = 0.f, defv = 0.f;
    {
      double r = (double)t * (double)RMAXF / (double)TBINS;
      double wfr = (double)(j+1) * M_PI / (double)RMAXF;
      double c = sqrt(2.0 / (double)RMAXF);
      double bess, dbess;
      if (r < 1e-12){ bess = c*wfr; dbess = 0.0; }
      else {
        double sw = sin(wfr*r), cw = cos(wfr*r);
        bess = c*sw/r;
        dbess = c*(wfr*cw*r - sw)/(r*r);
      }
      double xx = r / (double)RMAXF;
      double f = 0.0, df = 0.0;
      if (xx < 1.0){
        double x2 = xx*xx, x4 = x2*x2, x5 = x4*xx, x6 = x5*xx, x7 = x6*xx;
        f = 1.0 - 21.0*x5 + 35.0*x6 - 15.0*x7;
        df = (-105.0*x4 + 210.0*x5 - 105.0*x6) / (double)RMAXF;
      }
      efv  = (float)(bess*f);
      defv = (float)(dbess*f + bess*df);
    }
    const float* R1 = R1g + i*NBESS*KDIM;
    const float* R2 = R2g + i*KDIM*KDIM;
    const float* R3 = R3g + i*KDIM*KDIM;
    const float* R4 = R4g + i*KDIM*KDIM;
    float z = 0.f, dz = 0.f;
    #pragma unroll
    for (int b = 0; b < NBESS; b++){
      float ef = __shfl(efv, b), def = __shfl(defv, b);
      float wv = R1[b*KDIM+j];
      z += ef*wv; dz += def*wv;
    }
    float v = siluf(z), dv = dsiluf(z)*dz;
    z = 0.f; dz = 0.f;
    for (int k = 0; k < KDIM; k++){
      float xv = __shfl(v, k), dxv = __shfl(dv, k);
      float wv = R2[k*KDIM+j];
      z += xv*wv; dz += dxv*wv;
    }
    float v2 = siluf(z), dv2 = dsiluf(z)*dz;
    z = 0.f; dz = 0.f;
    for (int k = 0; k < KDIM; k++){
      float xv = __shfl(v2, k), dxv = __shfl(dv2, k);
      float wv = R3[k*KDIM+j];
      z += xv*wv; dz += dxv*wv;
    }
    float v3 = siluf(z), dv3 = dsiluf(z)*dz;
    z = 0.f; dz = 0.f;
    for (int k = 0; k < KDIM; k++){
      float xv = __shfl(v3, k), dxv = __shfl(dv3, k);
      float wv = R4[k*KDIM+j];
      z += xv*wv; dz += dxv*wv;
    }
    float2* Ft = i ? Ft2_1 : Ft2_0;
    Ft[t*KDIM+j].x = z;  if (t > 0) Ft[(t-1)*KDIM+j].y = z;
    dF4f[(t*KDIM+j)*4 + 2*i] = dz;
    if (t > 0) dF4f[((t-1)*KDIM+j)*4 + 2*i + 1] = dz;
  }
}

__global__ __launch_bounds__(256) void k_edge_setup(const float* pos, const float* shifts, const int* ei,
                                                    const int* z_buf,
                                                    float4* evec, int4* emeta,
                                                    int* cnt_r, int* cnt_s){
  int e = blockIdx.x*256 + threadIdx.x;
  int s = ei[e], rcv = ei[N_EDGES + e];
  float dx = pos[rcv*3+0] - pos[s*3+0] + shifts[e*3+0];
  float dy = pos[rcv*3+1] - pos[s*3+1] + shifts[e*3+1];
  float dz = pos[rcv*3+2] - pos[s*3+2] + shifts[e*3+2];
  float r = sqrtf(dx*dx + dy*dy + dz*dz + 1e-9f);
  evec[e] = make_float4(dx, dy, dz, r);
  emeta[e] = make_int4(__float_as_int(r), s, rcv, z_buf[s]);
  if (r < RMAXF){
    atomicAdd(&cnt_s[s], 1);
    atomicAdd(&cnt_r[rcv], 1);
  }
}

// shuffle-based scan: 2 barriers total
__global__ __launch_bounds__(1024) void k_scan(const int* cnt_r, int* ptr_r, int* cur_r,
                                               const int* cnt_s, int* ptr_s, int* cur_s){
  __shared__ float dummy;
  __shared__ int wtot[16];
  __shared__ int woff[16];
  (void)dummy;
  int tid = threadIdx.x;
  int w = tid >> 6, lane = tid & 63;
  const int* cnt = blockIdx.x ? cnt_s : cnt_r;
  int* ptr = blockIdx.x ? ptr_s : ptr_r;
  int* cur = blockIdx.x ? cur_s : cur_r;
  const int per = 10;
  int start = tid*per;
  int csum = 0;
  int cl[per];
  #pragma unroll
  for (int t = 0; t < per; t++){
    int i = start + t;
    int c = (i < N_NODES) ? cnt[i] : 0;
    cl[t] = c; csum += c;
  }
  // inclusive wave scan
  int v = csum;
  #pragma unroll
  for (int off = 1; off < 64; off <<= 1){
    int u = __shfl_up(v, off);
    if (lane >= off) v += u;
  }
  if (lane == 63) wtot[w] = v;
  __syncthreads();
  if (w == 0 && lane < 16){
    int t = wtot[lane];
    int sv = t;
    #pragma unroll
    for (int off = 1; off < 16; off <<= 1){
      int u = __shfl_up(sv, off);
      if (lane >= off) sv += u;
    }
    woff[lane] = sv - t;   // exclusive
    if (lane == 15) ptr[N_NODES] = sv;
  }
  __syncthreads();
  int run = woff[w] + v - csum;   // exclusive prefix for this thread
  #pragma unroll
  for (int t = 0; t < per; t++){
    int i = start + t;
    if (i < N_NODES){ ptr[i] = run; cur[i] = run; run += cl[t]; }
  }
}

__global__ __launch_bounds__(256) void k_fill(const int4* emeta, int* cur_r, int* cur_s,
                                              int4* pr_pack, int4* ps_pack){
  int e = blockIdx.x*256 + threadIdx.x;
  int4 m = emeta[e];            // {r_bits, snd, rcv, ez}
  float r = __int_as_float(m.x);
  if (r >= RMAXF) return;
  int p = atomicAdd(&cur_s[m.y], 1);
  ps_pack[p] = make_int4(m.x, m.z, e, 0);          // {r, rcv, eid}
  int p2 = atomicAdd(&cur_r[m.z], 1);
  pr_pack[p2] = make_int4(m.x, m.y, m.w, e);       // {r, snd, ez, eid}
}

// ---------------- layer-0: gather + cooperative epilogue ----------------
__global__ __launch_bounds__(256) void k_layer0_fwd(
    const int* z_buf, const int* ptr_r, const int4* pr_pack,
    const float2* Ft2, const float* M0,
    const float* Wout0, const float* theta0, const float* Wmix0,
    const float* Msc0, const float* w_read0,
    const float* Wup1, const float* Wsc1,
    float* A0_out, float* h1, float* sc1, float* e_node){
  __shared__ float lds_in[4][KDIM];
  __shared__ float lds_part[4][4][KDIM];
  int tid = threadIdx.x;
  int w = tid >> 6, lane = tid & 63;
  int node = blockIdx.x*4 + w;
  int z = z_buf[node];
  const float* rows = M0;
  float acc;
  GATHER_NODE(node, ptr_r, pr_pack, pk.z, LOADH_PLAIN, acc)
  acc *= (1.0f/AVG_NEI_F);
  float a0;
  COOPMV(acc, Wout0, a0)
  A0_out[node*KDIM+lane] = a0;
  float t0 = theta0[(0*ZDIM+z)*KDIM+lane];
  float t1 = theta0[(1*ZDIM+z)*KDIM+lane];
  float t2 = theta0[(2*ZDIM+z)*KDIM+lane];
  float v = (t0 + t1*a0 + t2*a0*a0)*a0;
  float f;
  COOPMV(v, Wmix0, f)
  f += Msc0[z*KDIM+lane];
  float p = waveReduce(f * w_read0[lane]);
  if (lane == 0) e_node[node] += p;
  float h;
  COOPMV(f, Wup1, h)
  h1[node*KDIM+lane] = h;
  const float* Wz = Wsc1 + z*KDIM*KDIM;   // z-dependent: per-wave
  float s;
  MV4R(f, Wz, s)
  sc1[node*KDIM+lane] = s;
}

// ---------------- layer-1 fwd + node-local bwd ----------------
__global__ __launch_bounds__(256) void k_layer1_fwd_bwd(
    const int* z_buf, const int* ptr_r, const int4* pr_pack,
    const float2* Ft2, const float* h1,
    const float* Wout1, const float* theta1, const float* Wmix1,
    const float* sc1, const float* Wr1, const float* Wr2,
    const float* P1, const float* Qtab, const float* WoT1, const float* w_read0,
    float2* gAr2, float* gF1, float* e_node){
  __shared__ float lds_in[4][KDIM];
  __shared__ float lds_part[4][4][KDIM];
  int tid = threadIdx.x;
  int w = tid >> 6, lane = tid & 63;
  int node = blockIdx.x*4 + w;
  int z = z_buf[node];
  const float* rows = h1;
  float acc;
  GATHER_NODE(node, ptr_r, pr_pack, pk.y, LOADH_PLAIN, acc)
  acc *= (1.0f/AVG_NEI_F);
  float a0;
  COOPMV(acc, Wout1, a0)
  float t0 = theta1[(0*ZDIM+z)*KDIM+lane];
  float t1 = theta1[(1*ZDIM+z)*KDIM+lane];
  float t2 = theta1[(2*ZDIM+z)*KDIM+lane];
  float v = (t0 + t1*a0 + t2*a0*a0)*a0;
  float f;
  COOPMV(v, Wmix1, f)
  f += sc1[node*KDIM+lane];
  // readout: t[hh] = sum_j f[j]*Wr1[j][hh]  (hh=lane&15, replicated x4)
  int hh = lane & 15;
  float tp0 = 0.f, tp1 = 0.f;
  for (int j = 0; j < KDIM; j += 2){
    tp0 += __shfl(f,j)  *Wr1[j*HIDR+hh];
    tp1 += __shfl(f,j+1)*Wr1[(j+1)*HIDR+hh];
  }
  float tpart = tp0 + tp1;
  float wr2 = Wr2[hh];
  float ne = waveReduce(siluf(tpart)*wr2);
  if (lane == 0) e_node[node] += 0.25f*ne;
  // backward through readout (low-rank shortcut)
  float coeff = dsiluf(tpart)*wr2;
  float gP0=0.f, gP1=0.f, gs0=0.f, gs1=0.f;
  const float* Qz = Qtab + z*HIDR*KDIM;
  #pragma unroll
  for (int h2 = 0; h2 < HIDR; h2 += 2){
    float c0 = __shfl(coeff, h2), c1 = __shfl(coeff, h2+1);
    gP0 += c0*P1[h2*KDIM+lane];
    gP1 += c1*P1[(h2+1)*KDIM+lane];
    gs0 += c0*Qz[h2*KDIM+lane];
    gs1 += c1*Qz[(h2+1)*KDIM+lane];
  }
  gF1[node*KDIM+lane] = w_read0[lane] + gs0 + gs1;
  float u = t0 + 2.f*t1*a0 + 3.f*t2*a0*a0;
  float vl = (gP0+gP1)*u;
  float gAr;
  COOPMV(vl, WoT1, gAr)
  gAr2[node*KDIM+lane].x = gAr * (1.0f/AVG_NEI_F);
}

// LDS pre-reduced energy
__global__ __launch_bounds__(256) void k_energy(const float* e_node, const int* batch, float* out_e){
  __shared__ float part[G_SEG];
  int tid = threadIdx.x;
  if (tid < G_SEG) part[tid] = 0.f;
  __syncthreads();
  int n = blockIdx.x*256 + tid;
  if (n < N_NODES) atomicAdd(&part[batch[n]], e_node[n]);
  __syncthreads();
  if (tid < G_SEG) atomicAdd(&out_e[tid], part[tid]);
}

// ---------------- bwd: sender-gather gH + layer-0 node bwd ----------------
__global__ __launch_bounds__(256) void k_bwd_gH0(
    const int* z_buf, const int* ptr_s, const int4* ps_pack,
    const float2* Ft2, const float2* gAr2c, const float* WupT1, const float* gF1,
    const float* A00, const float* WmixT0, const float* WoT0, const float* theta0,
    float2* gAr2){
  __shared__ float lds_in[4][KDIM];
  __shared__ float lds_part[4][4][KDIM];
  int tid = threadIdx.x;
  int w = tid >> 6, lane = tid & 63;
  int node = blockIdx.x*4 + w;
  float ga;
  GATHER_NODE(node, ptr_s, ps_pack, pk.y, LOADH_G2, ga)
  float gfh;
  COOPMV(ga, WupT1, gfh)
  float gt = gF1[node*KDIM+lane] + gfh;
  float gP;
  COOPMV(gt, WmixT0, gP)
  int z = z_buf[node];
  float a = A00[node*KDIM+lane];
  float t0 = theta0[(0*ZDIM+z)*KDIM+lane];
  float t1 = theta0[(1*ZDIM+z)*KDIM+lane];
  float t2 = theta0[(2*ZDIM+z)*KDIM+lane];
  float u = t0 + 2.f*t1*a + 3.f*t2*a*a;
  float vl = gP*u;
  float gAr;
  COOPMV(vl, WoT0, gAr)
  gAr2[node*KDIM+lane].y = gAr * (1.0f/AVG_NEI_F);
}

// per-edge gr/r -> evec[e].w  (one wave per edge; NO atomics)
__global__ __launch_bounds__(256) void k_gr(const int4* emeta, const float4* dF4,
                                            const float2* gAr2, const float* h1, const float* M0,
                                            float4* evec){
  int tid = threadIdx.x;
  int w = tid>>6, lane = tid&63;
  int e = blockIdx.x*4 + w;
  int4 m = emeta[e];              // {r, snd, rcv, ez}
  float r = __int_as_float(m.x);
  if (r >= RMAXF) return;
  float tp = r * (TBINS / RMAXF);
  int b = (int)tp; if (b > TBINS-1) b = TBINS-1;
  float fr = tp - (float)b;
  float4 d4 = dF4[b*KDIM + lane];
  float2 g  = gAr2[m.z*KDIM + lane];
  float hv1 = h1[m.y*KDIM + lane];
  float hv0 = M0[m.w*KDIM + lane];
  float v = g.x*hv1*(d4.z + fr*(d4.w - d4.z)) + g.y*hv0*(d4.x + fr*(d4.y - d4.x));
  v = waveReduce(v);
  if (lane == 0) evec[e].w = v / r;
}

// force gather: 16 lanes/node, both CSR lists, no atomics
__global__ __launch_bounds__(256) void k_force(const int* ptr_r, const int4* pr_pack,
                                               const int* ptr_s, const int4* ps_pack,
                                               const float4* evec,
                                               float* out_f){
  int tid = threadIdx.x;
  int node = blockIdx.x*16 + (tid >> 4);
  int li = tid & 15;
  float fx=0.f, fy=0.f, fz=0.f;
  int beg = ptr_r[node], end = ptr_r[node+1];
  for (int idx = beg + li; idx < end; idx += 16){
    int e = pr_pack[idx].w;
    float4 ev = evec[e];
    fx -= ev.w*ev.x; fy -= ev.w*ev.y; fz -= ev.w*ev.z;
  }
  beg = ptr_s[node]; end = ptr_s[node+1];
  for (int idx = beg + li; idx < end; idx += 16){
    int e = ps_pack[idx].z;
    float4 ev = evec[e];
    fx += ev.w*ev.x; fy += ev.w*ev.y; fz += ev.w*ev.z;
  }
  #pragma unroll
  for (int off = 8; off > 0; off >>= 1){
    fx += __shfl_xor(fx, off);
    fy += __shfl_xor(fy, off);
    fz += __shfl_xor(fz, off);
  }
  if (li == 0){
    out_f[node*3+0] = fx; out_f[node*3+1] = fy; out_f[node*3+2] = fz;
  }
}

extern "C" void kernel_launch(void* const* d_in, const int* in_sizes, int n_in,
                              void* d_out, int out_size, void* d_ws, size_t ws_size,
                              hipStream_t stream){
  const float* pos    = (const float*)d_in[0];
  const float* attrs  = (const float*)d_in[1];
  const float* shifts = (const float*)d_in[2];
  const float* aE     = (const float*)d_in[3];
  const float* We     = (const float*)d_in[4];
  const float* Wup    = (const float*)d_in[5];
  const float* R1     = (const float*)d_in[6];
  const float* R2     = (const float*)d_in[7];
  const float* R3     = (const float*)d_in[8];
  const float* R4     = (const float*)d_in[9];
  const float* Wout   = (const float*)d_in[10];
  const float* Wsc    = (const float*)d_in[11];
  const float* theta  = (const float*)d_in[12];
  const float* Wmix   = (const float*)d_in[13];
  const float* w_read0= (const float*)d_in[14];
  const float* Wr1    = (const float*)d_in[15];
  const float* Wr2    = (const float*)d_in[16];
  const int*   ei     = (const int*)d_in[17];
  const int*   batch  = (const int*)d_in[18];

  char* base = (char*)d_ws;
  size_t off = 0;
  auto alloc = [&](size_t bytes)->void*{
    void* p = base + off;
    off = (off + bytes + 255) & ~(size_t)255;
    return p;
  };
  float4* evec   = (float4*)alloc(N_EDGES*sizeof(float4));
  int4*   emeta  = (int4*)alloc(N_EDGES*sizeof(int4));
  int4*   pr_pack= (int4*)alloc(N_EDGES*sizeof(int4));
  int4*   ps_pack= (int4*)alloc(N_EDGES*sizeof(int4));
  float*  e_node = (float*)alloc(N_NODES*sizeof(float));
  float*  h1     = (float*)alloc(N_NODES*KDIM*sizeof(float));
  float*  sc1    = (float*)alloc(N_NODES*KDIM*sizeof(float));
  float*  A00    = (float*)alloc(N_NODES*KDIM*sizeof(float));
  float*  gF1    = (float*)alloc(N_NODES*KDIM*sizeof(float));
  float2* gAr2   = (float2*)alloc(N_NODES*KDIM*sizeof(float2));
  float2* Ft2_0  = (float2*)alloc((TBINS+1)*KDIM*sizeof(float2));
  float2* Ft2_1  = (float2*)alloc((TBINS+1)*KDIM*sizeof(float2));
  float4* dF4    = (float4*)alloc((TBINS+1)*KDIM*sizeof(float4));
  float*  M0     = (float*)alloc(ZDIM*KDIM*sizeof(float));
  float*  Msc0   = (float*)alloc(ZDIM*KDIM*sizeof(float));
  float*  WoT0   = (float*)alloc(KDIM*KDIM*sizeof(float));
  float*  WoT1   = (float*)alloc(KDIM*KDIM*sizeof(float));
  float*  WmixT0 = (float*)alloc(KDIM*KDIM*sizeof(float));
  float*  WupT1  = (float*)alloc(KDIM*KDIM*sizeof(float));
  float*  P1     = (float*)alloc(HIDR*KDIM*sizeof(float));
  float*  Qtab   = (float*)alloc(ZDIM*HIDR*KDIM*sizeof(float));
  int* z_buf = (int*)alloc(N_NODES*sizeof(int));
  int* cnt_r = (int*)alloc(N_NODES*sizeof(int));
  int* cnt_s = (int*)alloc(N_NODES*sizeof(int));
  int* ptr_r = (int*)alloc((N_NODES+1)*sizeof(int));
  int* ptr_s = (int*)alloc((N_NODES+1)*sizeof(int));
  int* cur_r = (int*)alloc(N_NODES*sizeof(int));
  int* cur_s = (int*)alloc(N_NODES*sizeof(int));

  float* out_e = (float*)d_out;
  float* out_f = out_e + G_SEG;

  hipMemsetAsync(d_out, 0, (size_t)out_size*sizeof(float), stream);
  hipMemsetAsync(cnt_r, 0, N_NODES*sizeof(int), stream);
  hipMemsetAsync(cnt_s, 0, N_NODES*sizeof(int), stream);

  const int NB4 = N_NODES/4;
  const int EB  = N_EDGES/256;
  const int EB4 = N_EDGES/4;
  const int NBt = (N_NODES+255)/256;

  const float* Wup1 = Wup + KDIM*KDIM;
  const float* Wsc1 = Wsc + ZDIM*KDIM*KDIM;
  const float* Wout1 = Wout + 3*KDIM*KDIM;
  const float* theta1 = theta + 3*ZDIM*KDIM;
  const float* Wmix1 = Wmix + KDIM*KDIM;

  k_setup<<<NSETUP,256,0,stream>>>(We, Wup, Wsc, Wout, Wmix, Wr1, attrs, aE,
                                   R1, R2, R3, R4,
                                   M0, Msc0, WoT0, WoT1, WmixT0, WupT1, P1, Qtab,
                                   Ft2_0, Ft2_1, (float*)dF4,
                                   z_buf, e_node);
  k_edge_setup<<<EB,256,0,stream>>>(pos, shifts, ei, z_buf, evec, emeta, cnt_r, cnt_s);
  k_scan<<<2,1024,0,stream>>>(cnt_r, ptr_r, cur_r, cnt_s, ptr_s, cur_s);
  k_fill<<<EB,256,0,stream>>>(emeta, cur_r, cur_s, pr_pack, ps_pack);

  // ---- forward ----
  k_layer0_fwd<<<NB4,256,0,stream>>>(z_buf, ptr_r, pr_pack, Ft2_0, M0,
      Wout, theta, Wmix, Msc0, w_read0, Wup1, Wsc1,
      A00, h1, sc1, e_node);
  k_layer1_fwd_bwd<<<NB4,256,0,stream>>>(z_buf, ptr_r, pr_pack, Ft2_1, h1,
      Wout1, theta1, Wmix1, sc1, Wr1, Wr2,
      P1, Qtab, WoT1, w_read0,
      gAr2, gF1, e_node);
  k_energy<<<NBt,256,0,stream>>>(e_node, batch, out_e);

  // ---- backward ----
  k_bwd_gH0<<<NB4,256,0,stream>>>(z_buf, ptr_s, ps_pack, Ft2_1, gAr2, WupT1, gF1,
      A00, WmixT0, WoT0, theta, gAr2);
  k_gr<<<EB4,256,0,stream>>>(emeta, dF4, gAr2, h1, M0, evec);
  k_force<<<N_NODES/16,256,0,stream>>>(ptr_r, pr_pack, ptr_s, ps_pack, evec, out_f);
}

// Round 15
// 265.280 us; speedup vs baseline: 1.3675x; 1.0006x over previous
//
#include <hip/hip_runtime.h>
#include <math.h>

#define N_NODES 10000
#define N_EDGES 160000
#define G_SEG 16
#define ZDIM 10
#define KDIM 64
#define NBESS 8
#define HIDR 16
#define RMAXF 5.0f
#define AVG_NEI_F 16.0f
#define TBINS 256
#define ZROW (TBINS+1)     // zeroed table row: padding lanes interpolate to exactly 0

__device__ __forceinline__ float siluf(float x){ float s = 1.0f/(1.0f+expf(-x)); return x*s; }
__device__ __forceinline__ float dsiluf(float x){ float s = 1.0f/(1.0f+expf(-x)); return s*(1.0f + x*(1.0f-s)); }

__device__ __forceinline__ float waveReduce(float v){
  for (int off = 32; off > 0; off >>= 1) v += __shfl_down(v, off);
  return v;
}

// per-node gather. Decode hoisted: each lane decodes ITS edge once; loop
// shuffles pre-decoded (bin, frac). Padding lanes -> ZROW (zero row), no mask.
#define GATHER_NODE(NODE, PTR, PACK, IDXEXPR, LOADH, OUT) { \
  int beg_ = PTR[NODE]; int deg_ = PTR[(NODE)+1] - beg_; \
  float a0_=0.f,a1_=0.f,a2_=0.f,a3_=0.f; \
  for (int base_=0; base_<deg_; base_+=64){ \
    int m_ = min(64, deg_-base_); \
    int b_l = ZROW; float f_l = 0.f; int ix_l = 0; \
    if (lane < m_){ \
      int4 pk = PACK[beg_+base_+lane]; \
      float tp_ = __int_as_float(pk.x) * (TBINS/RMAXF); \
      b_l = (int)tp_; f_l = tp_ - (float)b_l; ix_l = IDXEXPR; \
    } \
    int mr_ = (m_ + 7) & ~7; \
    for (int i_=0; i_<mr_; i_+=8){ \
      int b0_=__shfl(b_l,i_),   b1_=__shfl(b_l,i_+1), b2_=__shfl(b_l,i_+2), b3_=__shfl(b_l,i_+3); \
      int b4_=__shfl(b_l,i_+4), b5_=__shfl(b_l,i_+5), b6_=__shfl(b_l,i_+6), b7_=__shfl(b_l,i_+7); \
      float f0_=__shfl(f_l,i_),   f1_=__shfl(f_l,i_+1), f2_=__shfl(f_l,i_+2), f3_=__shfl(f_l,i_+3); \
      float f4_=__shfl(f_l,i_+4), f5_=__shfl(f_l,i_+5), f6_=__shfl(f_l,i_+6), f7_=__shfl(f_l,i_+7); \
      int s0_=__shfl(ix_l,i_),   s1_=__shfl(ix_l,i_+1), s2_=__shfl(ix_l,i_+2), s3_=__shfl(ix_l,i_+3); \
      int s4_=__shfl(ix_l,i_+4), s5_=__shfl(ix_l,i_+5), s6_=__shfl(ix_l,i_+6), s7_=__shfl(ix_l,i_+7); \
      float2 F0_=Ft2[b0_*KDIM+lane]; float h0_=LOADH(s0_); \
      float2 F1_=Ft2[b1_*KDIM+lane]; float h1_=LOADH(s1_); \
      float2 F2_=Ft2[b2_*KDIM+lane]; float h2_=LOADH(s2_); \
      float2 F3_=Ft2[b3_*KDIM+lane]; float h3_=LOADH(s3_); \
      float2 F4_=Ft2[b4_*KDIM+lane]; float h4_=LOADH(s4_); \
      float2 F5_=Ft2[b5_*KDIM+lane]; float h5_=LOADH(s5_); \
      float2 F6_=Ft2[b6_*KDIM+lane]; float h6_=LOADH(s6_); \
      float2 F7_=Ft2[b7_*KDIM+lane]; float h7_=LOADH(s7_); \
      a0_ += (F0_.x + f0_*(F0_.y-F0_.x))*h0_; a1_ += (F1_.x + f1_*(F1_.y-F1_.x))*h1_; \
      a2_ += (F2_.x + f2_*(F2_.y-F2_.x))*h2_; a3_ += (F3_.x + f3_*(F3_.y-F3_.x))*h3_; \
      a0_ += (F4_.x + f4_*(F4_.y-F4_.x))*h4_; a1_ += (F5_.x + f5_*(F5_.y-F5_.x))*h5_; \
      a2_ += (F6_.x + f6_*(F6_.y-F6_.x))*h6_; a3_ += (F7_.x + f7_*(F7_.y-F7_.x))*h7_; \
    } } \
  OUT = ((a0_+a1_)+(a2_+a3_)); }

// cooperative block matvec: 4 waves, 4 nodes; wave w loads W rows [16w,16w+16)
// ONCE and accumulates partials for all 4 nodes; combine via LDS.
#define COOPMV(INV, W, OUTV) { \
  lds_in[w][lane] = INV; \
  __syncthreads(); \
  { float p0_=0.f,p1_=0.f,p2_=0.f,p3__=0.f; \
    const float* Wb_ = (W) + (w*16)*KDIM + lane; \
    _Pragma("unroll") \
    for (int kk_=0; kk_<16; kk_++){ \
      float wrow_ = Wb_[kk_*KDIM]; \
      int k_ = w*16 + kk_; \
      p0_  += lds_in[0][k_]*wrow_; \
      p1_  += lds_in[1][k_]*wrow_; \
      p2_  += lds_in[2][k_]*wrow_; \
      p3__ += lds_in[3][k_]*wrow_; \
    } \
    lds_part[w][0][lane]=p0_; lds_part[w][1][lane]=p1_; \
    lds_part[w][2][lane]=p2_; lds_part[w][3][lane]=p3__; } \
  __syncthreads(); \
  OUTV = ((lds_part[0][w][lane]+lds_part[1][w][lane]) + \
          (lds_part[2][w][lane]+lds_part[3][w][lane])); }

// per-wave K=64 matvec from register V via uniform shfl (for z-dependent W)
#define MV4R(V, W, OUT) { \
  float x0_=0.f,x1_=0.f,x2_=0.f,x3_=0.f; \
  for (int k_=0;k_<KDIM;k_+=4){ \
    x0_ += __shfl(V,k_)  *W[k_*KDIM+lane]; \
    x1_ += __shfl(V,k_+1)*W[(k_+1)*KDIM+lane]; \
    x2_ += __shfl(V,k_+2)*W[(k_+2)*KDIM+lane]; \
    x3_ += __shfl(V,k_+3)*W[(k_+3)*KDIM+lane]; \
  } OUT = (x0_+x1_)+(x2_+x3_); }

#define LOADH_PLAIN(S) rows[(S)*KDIM + lane]
#define LOADH_G2(S)    gAr2c[(S)*KDIM + lane].x

#define NTABW 514            // 2 layers x 257 bins, one wave each
#define SETUP_BASE 153
#define NSETUP (SETUP_BASE + (NTABW+3)/4)   // 153 + 129 = 282 blocks

// ---------------- merged setup + wave-local table build ----------------
__global__ __launch_bounds__(256) void k_setup(
    const float* We, const float* Wup, const float* Wsc,
    const float* Wout, const float* Wmix,
    const float* Wr1,
    const float* attrs, const float* aE,
    const float* R1g, const float* R2g, const float* R3g, const float* R4g,
    float* M0, float* Msc0,
    float* WoT0, float* WoT1, float* WmixT0, float* WupT1,
    float* P1, float* Qtab,
    float2* Ft2_0, float2* Ft2_1, float* dF4f,
    int* z_buf, float* e_node){
  int blk = blockIdx.x, tid = threadIdx.x;
  const float* Wmix1 = Wmix + KDIM*KDIM;
  const float* Wsc1  = Wsc + ZDIM*KDIM*KDIM;
  if (blk < 5){
    int idx = blk*256 + tid;
    if (idx < 1280){
      int which = idx >= 640;
      int t = which ? idx - 640 : idx;
      int z = t >> 6, j = t & 63;
      float acc = 0.f;
      if (!which){
        #pragma unroll 8
        for (int k = 0; k < KDIM; k++) acc += We[z*KDIM + k] * Wup[k*KDIM + j];
        M0[z*KDIM + j] = acc;
      } else {
        #pragma unroll 8
        for (int k = 0; k < KDIM; k++) acc += We[z*KDIM + k] * Wsc[(z*KDIM + k)*KDIM + j];
        Msc0[z*KDIM + j] = acc;
      }
    }
  } else if (blk < 69){
    int t = (blk-5)*256 + tid;   // 0..16383
    int arr = t >> 12;
    int rem = t & 4095;
    int j = rem >> 6, k = rem & 63;
    float v; float* dst;
    switch(arr){
      case 0: v = Wout[k*KDIM + j];                 dst = WoT0;   break;
      case 1: v = Wout[3*KDIM*KDIM + k*KDIM + j];   dst = WoT1;   break;
      case 2: v = Wmix[k*KDIM + j];                 dst = WmixT0; break;
      default:v = Wup[KDIM*KDIM + k*KDIM + j];      dst = WupT1;  break;
    }
    dst[rem] = v;
  } else if (blk < 73){
    int t = (blk-69)*256 + tid;  // 0..1023
    int h = t >> 6, k = t & 63;
    float acc = 0.f;
    #pragma unroll 8
    for (int j = 0; j < KDIM; j++) acc += Wr1[j*HIDR + h] * Wmix1[k*KDIM + j];
    P1[h*KDIM + k] = acc;
  } else if (blk < 113){
    int t = (blk-73)*256 + tid;  // 0..10239
    int z = t >> 10;
    int rem = t & 1023;
    int h = rem >> 6, k = rem & 63;
    float acc = 0.f;
    #pragma unroll 8
    for (int j = 0; j < KDIM; j++) acc += Wr1[j*HIDR + h] * Wsc1[(z*KDIM + k)*KDIM + j];
    Qtab[(z*HIDR + h)*KDIM + k] = acc;
  } else if (blk < SETUP_BASE){
    int n = (blk-113)*256 + tid;
    if (n < N_NODES){
      int z = 0;
      for (int i = 1; i < ZDIM; i++) if (attrs[n*ZDIM+i] > 0.5f) z = i;
      z_buf[n] = z;
      e_node[n] = aE[z];
    }
  } else {
    // wave-local radial-MLP table build: one (layer,bin) per wave, no barriers
    int w = tid >> 6, j = tid & 63;
    int wave_id = (blk - SETUP_BASE)*4 + w;
    if (wave_id >= NTABW) return;
    int i = wave_id / (TBINS+1);
    int t = wave_id % (TBINS+1);
    float efv = 0.f, defv = 0.f;
    {
      double r = (double)t * (double)RMAXF / (double)TBINS;
      double wfr = (double)(j+1) * M_PI / (double)RMAXF;
      double c = sqrt(2.0 / (double)RMAXF);
      double bess, dbess;
      if (r < 1e-12){ bess = c*wfr; dbess = 0.0; }
      else {
        double sw = sin(wfr*r), cw = cos(wfr*r);
        bess = c*sw/r;
        dbess = c*(wfr*cw*r - sw)/(r*r);
      }
      double xx = r / (double)RMAXF;
      double f = 0.0, df = 0.0;
      if (xx < 1.0){
        double x2 = xx*xx, x4 = x2*x2, x5 = x4*xx, x6 = x5*xx, x7 = x6*xx;
        f = 1.0 - 21.0*x5 + 35.0*x6 - 15.0*x7;
        df = (-105.0*x4 + 210.0*x5 - 105.0*x6) / (double)RMAXF;
      }
      efv  = (float)(bess*f);
      defv = (float)(dbess*f + bess*df);
    }
    const float* R1 = R1g + i*NBESS*KDIM;
    const float* R2 = R2g + i*KDIM*KDIM;
    const float* R3 = R3g + i*KDIM*KDIM;
    const float* R4 = R4g + i*KDIM*KDIM;
    float z = 0.f, dz = 0.f;
    #pragma unroll
    for (int b = 0; b < NBESS; b++){
      float ef = __shfl(efv, b), def = __shfl(defv, b);
      float wv = R1[b*KDIM+j];
      z += ef*wv; dz += def*wv;
    }
    float v = siluf(z), dv = dsiluf(z)*dz;
    z = 0.f; dz = 0.f;
    for (int k = 0; k < KDIM; k++){
      float xv = __shfl(v, k), dxv = __shfl(dv, k);
      float wv = R2[k*KDIM+j];
      z += xv*wv; dz += dxv*wv;
    }
    float v2 = siluf(z), dv2 = dsiluf(z)*dz;
    z = 0.f; dz = 0.f;
    for (int k = 0; k < KDIM; k++){
      float xv = __shfl(v2, k), dxv = __shfl(dv2, k);
      float wv = R3[k*KDIM+j];
      z += xv*wv; dz += dxv*wv;
    }
    float v3 = siluf(z), dv3 = dsiluf(z)*dz;
    z = 0.f; dz = 0.f;
    for (int k = 0; k < KDIM; k++){
      float xv = __shfl(v3, k), dxv = __shfl(dv3, k);
      float wv = R4[k*KDIM+j];
      z += xv*wv; dz += dxv*wv;
    }
    float2* Ft = i ? Ft2_1 : Ft2_0;
    Ft[t*KDIM+j].x = z;  if (t > 0) Ft[(t-1)*KDIM+j].y = z;
    dF4f[(t*KDIM+j)*4 + 2*i] = dz;
    if (t > 0) dF4f[((t-1)*KDIM+j)*4 + 2*i + 1] = dz;
    if (t == 0) Ft[ZROW*KDIM + j] = make_float2(0.f, 0.f);   // zero row for padding lanes
  }
}

__global__ __launch_bounds__(256) void k_edge_setup(const float* pos, const float* shifts, const int* ei,
                                                    const int* z_buf,
                                                    float4* evec, int4* emeta,
                                                    int* cnt_r, int* cnt_s){
  int e = blockIdx.x*256 + threadIdx.x;
  int s = ei[e], rcv = ei[N_EDGES + e];
  float dx = pos[rcv*3+0] - pos[s*3+0] + shifts[e*3+0];
  float dy = pos[rcv*3+1] - pos[s*3+1] + shifts[e*3+1];
  float dz = pos[rcv*3+2] - pos[s*3+2] + shifts[e*3+2];
  float r = sqrtf(dx*dx + dy*dy + dz*dz + 1e-9f);
  evec[e] = make_float4(dx, dy, dz, r);
  emeta[e] = make_int4(__float_as_int(r), s, rcv, z_buf[s]);
  if (r < RMAXF){
    atomicAdd(&cnt_s[s], 1);
    atomicAdd(&cnt_r[rcv], 1);
  }
}

// shuffle-based scan: 2 barriers total
__global__ __launch_bounds__(1024) void k_scan(const int* cnt_r, int* ptr_r, int* cur_r,
                                               const int* cnt_s, int* ptr_s, int* cur_s){
  __shared__ int wtot[16];
  __shared__ int woff[16];
  int tid = threadIdx.x;
  int w = tid >> 6, lane = tid & 63;
  const int* cnt = blockIdx.x ? cnt_s : cnt_r;
  int* ptr = blockIdx.x ? ptr_s : ptr_r;
  int* cur = blockIdx.x ? cur_s : cur_r;
  const int per = 10;
  int start = tid*per;
  int csum = 0;
  int cl[per];
  #pragma unroll
  for (int t = 0; t < per; t++){
    int i = start + t;
    int c = (i < N_NODES) ? cnt[i] : 0;
    cl[t] = c; csum += c;
  }
  int v = csum;
  #pragma unroll
  for (int off = 1; off < 64; off <<= 1){
    int u = __shfl_up(v, off);
    if (lane >= off) v += u;
  }
  if (lane == 63) wtot[w] = v;
  __syncthreads();
  if (w == 0 && lane < 16){
    int t = wtot[lane];
    int sv = t;
    #pragma unroll
    for (int off = 1; off < 16; off <<= 1){
      int u = __shfl_up(sv, off);
      if (lane >= off) sv += u;
    }
    woff[lane] = sv - t;
    if (lane == 15) ptr[N_NODES] = sv;
  }
  __syncthreads();
  int run = woff[w] + v - csum;
  #pragma unroll
  for (int t = 0; t < per; t++){
    int i = start + t;
    if (i < N_NODES){ ptr[i] = run; cur[i] = run; run += cl[t]; }
  }
}

__global__ __launch_bounds__(256) void k_fill(const int4* emeta, int* cur_r, int* cur_s,
                                              int4* pr_pack, int4* ps_pack){
  int e = blockIdx.x*256 + threadIdx.x;
  int4 m = emeta[e];            // {r_bits, snd, rcv, ez}
  float r = __int_as_float(m.x);
  if (r >= RMAXF) return;
  int p = atomicAdd(&cur_s[m.y], 1);
  ps_pack[p] = make_int4(m.x, m.z, e, 0);          // {r, rcv, eid}
  int p2 = atomicAdd(&cur_r[m.z], 1);
  pr_pack[p2] = make_int4(m.x, m.y, m.w, e);       // {r, snd, ez, eid}
}

// ---------------- layer-0: gather + cooperative epilogue ----------------
__global__ __launch_bounds__(256) void k_layer0_fwd(
    const int* z_buf, const int* ptr_r, const int4* pr_pack,
    const float2* Ft2, const float* M0,
    const float* Wout0, const float* theta0, const float* Wmix0,
    const float* Msc0, const float* w_read0,
    const float* Wup1, const float* Wsc1,
    float* A0_out, float* h1, float* sc1, float* e_node){
  __shared__ float lds_in[4][KDIM];
  __shared__ float lds_part[4][4][KDIM];
  int tid = threadIdx.x;
  int w = tid >> 6, lane = tid & 63;
  int node = blockIdx.x*4 + w;
  int z = z_buf[node];
  const float* rows = M0;
  float acc;
  GATHER_NODE(node, ptr_r, pr_pack, pk.z, LOADH_PLAIN, acc)
  acc *= (1.0f/AVG_NEI_F);
  float a0;
  COOPMV(acc, Wout0, a0)
  A0_out[node*KDIM+lane] = a0;
  float t0 = theta0[(0*ZDIM+z)*KDIM+lane];
  float t1 = theta0[(1*ZDIM+z)*KDIM+lane];
  float t2 = theta0[(2*ZDIM+z)*KDIM+lane];
  float v = (t0 + t1*a0 + t2*a0*a0)*a0;
  float f;
  COOPMV(v, Wmix0, f)
  f += Msc0[z*KDIM+lane];
  float p = waveReduce(f * w_read0[lane]);
  if (lane == 0) e_node[node] += p;
  float h;
  COOPMV(f, Wup1, h)
  h1[node*KDIM+lane] = h;
  const float* Wz = Wsc1 + z*KDIM*KDIM;   // z-dependent: per-wave
  float s;
  MV4R(f, Wz, s)
  sc1[node*KDIM+lane] = s;
}

// ---------------- layer-1 fwd + node-local bwd ----------------
__global__ __launch_bounds__(256) void k_layer1_fwd_bwd(
    const int* z_buf, const int* ptr_r, const int4* pr_pack,
    const float2* Ft2, const float* h1,
    const float* Wout1, const float* theta1, const float* Wmix1,
    const float* sc1, const float* Wr1, const float* Wr2,
    const float* P1, const float* Qtab, const float* WoT1, const float* w_read0,
    float2* gAr2, float* gF1, float* e_node){
  __shared__ float lds_in[4][KDIM];
  __shared__ float lds_part[4][4][KDIM];
  int tid = threadIdx.x;
  int w = tid >> 6, lane = tid & 63;
  int node = blockIdx.x*4 + w;
  int z = z_buf[node];
  const float* rows = h1;
  float acc;
  GATHER_NODE(node, ptr_r, pr_pack, pk.y, LOADH_PLAIN, acc)
  acc *= (1.0f/AVG_NEI_F);
  float a0;
  COOPMV(acc, Wout1, a0)
  float t0 = theta1[(0*ZDIM+z)*KDIM+lane];
  float t1 = theta1[(1*ZDIM+z)*KDIM+lane];
  float t2 = theta1[(2*ZDIM+z)*KDIM+lane];
  float v = (t0 + t1*a0 + t2*a0*a0)*a0;
  float f;
  COOPMV(v, Wmix1, f)
  f += sc1[node*KDIM+lane];
  int hh = lane & 15;
  float tp0 = 0.f, tp1 = 0.f;
  for (int j = 0; j < KDIM; j += 2){
    tp0 += __shfl(f,j)  *Wr1[j*HIDR+hh];
    tp1 += __shfl(f,j+1)*Wr1[(j+1)*HIDR+hh];
  }
  float tpart = tp0 + tp1;
  float wr2 = Wr2[hh];
  float ne = waveReduce(siluf(tpart)*wr2);
  if (lane == 0) e_node[node] += 0.25f*ne;
  float coeff = dsiluf(tpart)*wr2;
  float gP0=0.f, gP1=0.f, gs0=0.f, gs1=0.f;
  const float* Qz = Qtab + z*HIDR*KDIM;
  #pragma unroll
  for (int h2 = 0; h2 < HIDR; h2 += 2){
    float c0 = __shfl(coeff, h2), c1 = __shfl(coeff, h2+1);
    gP0 += c0*P1[h2*KDIM+lane];
    gP1 += c1*P1[(h2+1)*KDIM+lane];
    gs0 += c0*Qz[h2*KDIM+lane];
    gs1 += c1*Qz[(h2+1)*KDIM+lane];
  }
  gF1[node*KDIM+lane] = w_read0[lane] + gs0 + gs1;
  float u = t0 + 2.f*t1*a0 + 3.f*t2*a0*a0;
  float vl = (gP0+gP1)*u;
  float gAr;
  COOPMV(vl, WoT1, gAr)
  gAr2[node*KDIM+lane].x = gAr * (1.0f/AVG_NEI_F);
}

// LDS pre-reduced energy
__global__ __launch_bounds__(256) void k_energy(const float* e_node, const int* batch, float* out_e){
  __shared__ float part[G_SEG];
  int tid = threadIdx.x;
  if (tid < G_SEG) part[tid] = 0.f;
  __syncthreads();
  int n = blockIdx.x*256 + tid;
  if (n < N_NODES) atomicAdd(&part[batch[n]], e_node[n]);
  __syncthreads();
  if (tid < G_SEG) atomicAdd(&out_e[tid], part[tid]);
}

// ---------------- bwd: sender-gather gH + layer-0 node bwd ----------------
__global__ __launch_bounds__(256) void k_bwd_gH0(
    const int* z_buf, const int* ptr_s, const int4* ps_pack,
    const float2* Ft2, const float2* gAr2c, const float* WupT1, const float* gF1,
    const float* A00, const float* WmixT0, const float* WoT0, const float* theta0,
    float2* gAr2){
  __shared__ float lds_in[4][KDIM];
  __shared__ float lds_part[4][4][KDIM];
  int tid = threadIdx.x;
  int w = tid >> 6, lane = tid & 63;
  int node = blockIdx.x*4 + w;
  float ga;
  GATHER_NODE(node, ptr_s, ps_pack, pk.y, LOADH_G2, ga)
  float gfh;
  COOPMV(ga, WupT1, gfh)
  float gt = gF1[node*KDIM+lane] + gfh;
  float gP;
  COOPMV(gt, WmixT0, gP)
  int z = z_buf[node];
  float a = A00[node*KDIM+lane];
  float t0 = theta0[(0*ZDIM+z)*KDIM+lane];
  float t1 = theta0[(1*ZDIM+z)*KDIM+lane];
  float t2 = theta0[(2*ZDIM+z)*KDIM+lane];
  float u = t0 + 2.f*t1*a + 3.f*t2*a*a;
  float vl = gP*u;
  float gAr;
  COOPMV(vl, WoT0, gAr)
  gAr2[node*KDIM+lane].y = gAr * (1.0f/AVG_NEI_F);
}

// per-edge gr/r -> evec[e].w  (one wave per edge; NO atomics)
__global__ __launch_bounds__(256) void k_gr(const int4* emeta, const float4* dF4,
                                            const float2* gAr2, const float* h1, const float* M0,
                                            float4* evec){
  int tid = threadIdx.x;
  int w = tid>>6, lane = tid&63;
  int e = blockIdx.x*4 + w;
  int4 m = emeta[e];              // {r, snd, rcv, ez}
  float r = __int_as_float(m.x);
  if (r >= RMAXF) return;
  float tp = r * (TBINS / RMAXF);
  int b = (int)tp; if (b > TBINS-1) b = TBINS-1;
  float fr = tp - (float)b;
  float4 d4 = dF4[b*KDIM + lane];
  float2 g  = gAr2[m.z*KDIM + lane];
  float hv1 = h1[m.y*KDIM + lane];
  float hv0 = M0[m.w*KDIM + lane];
  float v = g.x*hv1*(d4.z + fr*(d4.w - d4.z)) + g.y*hv0*(d4.x + fr*(d4.y - d4.x));
  v = waveReduce(v);
  if (lane == 0) evec[e].w = v / r;
}

// force gather: 16 lanes/node, both CSR lists, no atomics
__global__ __launch_bounds__(256) void k_force(const int* ptr_r, const int4* pr_pack,
                                               const int* ptr_s, const int4* ps_pack,
                                               const float4* evec,
                                               float* out_f){
  int tid = threadIdx.x;
  int node = blockIdx.x*16 + (tid >> 4);
  int li = tid & 15;
  float fx=0.f, fy=0.f, fz=0.f;
  int beg = ptr_r[node], end = ptr_r[node+1];
  for (int idx = beg + li; idx < end; idx += 16){
    int e = pr_pack[idx].w;
    float4 ev = evec[e];
    fx -= ev.w*ev.x; fy -= ev.w*ev.y; fz -= ev.w*ev.z;
  }
  beg = ptr_s[node]; end = ptr_s[node+1];
  for (int idx = beg + li; idx < end; idx += 16){
    int e = ps_pack[idx].z;
    float4 ev = evec[e];
    fx += ev.w*ev.x; fy += ev.w*ev.y; fz += ev.w*ev.z;
  }
  #pragma unroll
  for (int off = 8; off > 0; off >>= 1){
    fx += __shfl_xor(fx, off);
    fy += __shfl_xor(fy, off);
    fz += __shfl_xor(fz, off);
  }
  if (li == 0){
    out_f[node*3+0] = fx; out_f[node*3+1] = fy; out_f[node*3+2] = fz;
  }
}

extern "C" void kernel_launch(void* const* d_in, const int* in_sizes, int n_in,
                              void* d_out, int out_size, void* d_ws, size_t ws_size,
                              hipStream_t stream){
  const float* pos    = (const float*)d_in[0];
  const float* attrs  = (const float*)d_in[1];
  const float* shifts = (const float*)d_in[2];
  const float* aE     = (const float*)d_in[3];
  const float* We     = (const float*)d_in[4];
  const float* Wup    = (const float*)d_in[5];
  const float* R1     = (const float*)d_in[6];
  const float* R2     = (const float*)d_in[7];
  const float* R3     = (const float*)d_in[8];
  const float* R4     = (const float*)d_in[9];
  const float* Wout   = (const float*)d_in[10];
  const float* Wsc    = (const float*)d_in[11];
  const float* theta  = (const float*)d_in[12];
  const float* Wmix   = (const float*)d_in[13];
  const float* w_read0= (const float*)d_in[14];
  const float* Wr1    = (const float*)d_in[15];
  const float* Wr2    = (const float*)d_in[16];
  const int*   ei     = (const int*)d_in[17];
  const int*   batch  = (const int*)d_in[18];

  char* base = (char*)d_ws;
  size_t off = 0;
  auto alloc = [&](size_t bytes)->void*{
    void* p = base + off;
    off = (off + bytes + 255) & ~(size_t)255;
    return p;
  };
  float4* evec   = (float4*)alloc(N_EDGES*sizeof(float4));
  int4*   emeta  = (int4*)alloc(N_EDGES*sizeof(int4));
  int4*   pr_pack= (int4*)alloc(N_EDGES*sizeof(int4));
  int4*   ps_pack= (int4*)alloc(N_EDGES*sizeof(int4));
  float*  e_node = (float*)alloc(N_NODES*sizeof(float));
  float*  h1     = (float*)alloc(N_NODES*KDIM*sizeof(float));
  float*  sc1    = (float*)alloc(N_NODES*KDIM*sizeof(float));
  float*  A00    = (float*)alloc(N_NODES*KDIM*sizeof(float));
  float*  gF1    = (float*)alloc(N_NODES*KDIM*sizeof(float));
  float2* gAr2   = (float2*)alloc(N_NODES*KDIM*sizeof(float2));
  float2* Ft2_0  = (float2*)alloc((TBINS+2)*KDIM*sizeof(float2));
  float2* Ft2_1  = (float2*)alloc((TBINS+2)*KDIM*sizeof(float2));
  float4* dF4    = (float4*)alloc((TBINS+1)*KDIM*sizeof(float4));
  float*  M0     = (float*)alloc(ZDIM*KDIM*sizeof(float));
  float*  Msc0   = (float*)alloc(ZDIM*KDIM*sizeof(float));
  float*  WoT0   = (float*)alloc(KDIM*KDIM*sizeof(float));
  float*  WoT1   = (float*)alloc(KDIM*KDIM*sizeof(float));
  float*  WmixT0 = (float*)alloc(KDIM*KDIM*sizeof(float));
  float*  WupT1  = (float*)alloc(KDIM*KDIM*sizeof(float));
  float*  P1     = (float*)alloc(HIDR*KDIM*sizeof(float));
  float*  Qtab   = (float*)alloc(ZDIM*HIDR*KDIM*sizeof(float));
  int* z_buf = (int*)alloc(N_NODES*sizeof(int));
  int* cnt_r = (int*)alloc(N_NODES*sizeof(int));
  int* cnt_s = (int*)alloc(N_NODES*sizeof(int));
  int* ptr_r = (int*)alloc((N_NODES+1)*sizeof(int));
  int* ptr_s = (int*)alloc((N_NODES+1)*sizeof(int));
  int* cur_r = (int*)alloc(N_NODES*sizeof(int));
  int* cur_s = (int*)alloc(N_NODES*sizeof(int));

  float* out_e = (float*)d_out;
  float* out_f = out_e + G_SEG;

  hipMemsetAsync(d_out, 0, (size_t)out_size*sizeof(float), stream);
  hipMemsetAsync(cnt_r, 0, N_NODES*sizeof(int), stream);
  hipMemsetAsync(cnt_s, 0, N_NODES*sizeof(int), stream);

  const int NB4 = N_NODES/4;
  const int EB  = N_EDGES/256;
  const int EB4 = N_EDGES/4;
  const int NBt = (N_NODES+255)/256;

  const float* Wup1 = Wup + KDIM*KDIM;
  const float* Wsc1 = Wsc + ZDIM*KDIM*KDIM;
  const float* Wout1 = Wout + 3*KDIM*KDIM;
  const float* theta1 = theta + 3*ZDIM*KDIM;
  const float* Wmix1 = Wmix + KDIM*KDIM;

  k_setup<<<NSETUP,256,0,stream>>>(We, Wup, Wsc, Wout, Wmix, Wr1, attrs, aE,
                                   R1, R2, R3, R4,
                                   M0, Msc0, WoT0, WoT1, WmixT0, WupT1, P1, Qtab,
                                   Ft2_0, Ft2_1, (float*)dF4,
                                   z_buf, e_node);
  k_edge_setup<<<EB,256,0,stream>>>(pos, shifts, ei, z_buf, evec, emeta, cnt_r, cnt_s);
  k_scan<<<2,1024,0,stream>>>(cnt_r, ptr_r, cur_r, cnt_s, ptr_s, cur_s);
  k_fill<<<EB,256,0,stream>>>(emeta, cur_r, cur_s, pr_pack, ps_pack);

  // ---- forward ----
  k_layer0_fwd<<<NB4,256,0,stream>>>(z_buf, ptr_r, pr_pack, Ft2_0, M0,
      Wout, theta, Wmix, Msc0, w_read0, Wup1, Wsc1,
      A00, h1, sc1, e_node);
  k_layer1_fwd_bwd<<<NB4,256,0,stream>>>(z_buf, ptr_r, pr_pack, Ft2_1, h1,
      Wout1, theta1, Wmix1, sc1, Wr1, Wr2,
      P1, Qtab, WoT1, w_read0,
      gAr2, gF1, e_node);
  k_energy<<<NBt,256,0,stream>>>(e_node, batch, out_e);

  // ---- backward ----
  k_bwd_gH0<<<NB4,256,0,stream>>>(z_buf, ptr_s, ps_pack, Ft2_1, gAr2, WupT1, gF1,
      A00, WmixT0, WoT0, theta, gAr2);
  k_gr<<<EB4,256,0,stream>>>(emeta, dF4, gAr2, h1, M0, evec);
  k_force<<<N_NODES/16,256,0,stream>>>(ptr_r, pr_pack, ptr_s, ps_pack, evec, out_f);
}